// Round 4
// baseline (236.567 us; speedup 1.0000x reference)
//
#include <hip/hip_runtime.h>

#define TOK 16384
#define DD 1024
#define OO 1024
#define KE 1056     // 1024 + 16 lora cols + 16 pad
#define CLAMPV 4.605170185988091f

// gate tiling
#define GROWS 64                // rows per gate block
#define GBK 32                  // K chunk per stage
#define WSLAB 516               // floats per col-group slab (32k*16 + 4 pad)
#define WTILE 9216              // 17*516 = 8772, padded to 36*256
#define WCHUNK 36               // 256-float wave-uniform chunks per kt tile
#define XSTR 68                 // x tile row stride (64 rows + 4 pad)
#define XTILE (GBK * XSTR)      // 2176 floats
#define BUFSZ (XTILE + WTILE)   // 11392 floats per buffer (45568 B)

typedef __attribute__((ext_vector_type(8))) short short8;
typedef __attribute__((ext_vector_type(4))) float f32x4;

__device__ __forceinline__ unsigned short f2bf(float f) {
  unsigned int u = __float_as_uint(f);
  return (unsigned short)((u + 0x7FFFu + ((u >> 16) & 1u)) >> 16);
}

__device__ __forceinline__ void gload16(const unsigned short* g, unsigned short* l) {
  __builtin_amdgcn_global_load_lds(
      (const __attribute__((address_space(1))) void*)g,
      (__attribute__((address_space(3))) void*)l, 16, 0, 0);
}

__device__ __forceinline__ void gload16f(const float* g, float* l) {
  __builtin_amdgcn_global_load_lds(
      (const __attribute__((address_space(1))) void*)g,
      (__attribute__((address_space(3))) void*)l, 16, 0, 0);
}

__device__ __forceinline__ float down_val(int j, int d,
    const float* __restrict__ Wd0, const float* __restrict__ Wd1,
    const float* __restrict__ Wd2, const float* __restrict__ Wd3) {
  if (j == 0) return Wd0[d];
  if (j < 3) return Wd1[(j - 1) * DD + d];
  if (j < 7) return Wd2[(j - 3) * DD + d];
  if (j < 15) return Wd3[(j - 7) * DD + d];
  return 0.f;
}

// ---------------- kernel 0: prep (WtL blocked fp32, Bx bf16, Ax pad, simn) ----------------
__global__ __launch_bounds__(256) void prep2(
    const float* __restrict__ W, const float* __restrict__ Wp,
    const float* __restrict__ sim,
    const float* __restrict__ Wd0, const float* __restrict__ Wd1,
    const float* __restrict__ Wd2, const float* __restrict__ Wd3,
    const float* __restrict__ Wu0, const float* __restrict__ Wu1,
    const float* __restrict__ Wu2, const float* __restrict__ Wu3,
    float* __restrict__ WtL, unsigned short* __restrict__ Bx,
    unsigned short* __restrict__ Ax, float* __restrict__ simn) {
  __shared__ float part[4][4];
  if (blockIdx.x == 0) {
    // simn = sim / ||sim col||  (sim is [256][4] row-major)
    int t = threadIdx.x;
    float4 sv = *(const float4*)&sim[t * 4];
    float v[4] = {sv.x * sv.x, sv.y * sv.y, sv.z * sv.z, sv.w * sv.w};
#pragma unroll
    for (int off = 1; off < 64; off <<= 1) {
#pragma unroll
      for (int e = 0; e < 4; ++e) v[e] += __shfl_xor(v[e], off, 64);
    }
    int wv = t >> 6, ln = t & 63;
    if (ln == 0) { part[wv][0] = v[0]; part[wv][1] = v[1]; part[wv][2] = v[2]; part[wv][3] = v[3]; }
    __syncthreads();
    float4 o;
    o.x = sv.x / fmaxf(sqrtf(part[0][0] + part[1][0] + part[2][0] + part[3][0]), 1e-12f);
    o.y = sv.y / fmaxf(sqrtf(part[0][1] + part[1][1] + part[2][1] + part[3][1]), 1e-12f);
    o.z = sv.z / fmaxf(sqrtf(part[0][2] + part[1][2] + part[2][2] + part[3][2]), 1e-12f);
    o.w = sv.w / fmaxf(sqrtf(part[0][3] + part[1][3] + part[2][3] + part[3][3]), 1e-12f);
    *(float4*)&simn[t * 4] = o;
  }
  const int nWtL = 32 * WTILE;      // 294912
  const int nWb = OO * KE;          // 1081344
  const int nXpad = TOK * 16;       // 262144
  const int total = nWtL + nWb + nXpad;
  for (int i = blockIdx.x * 256 + threadIdx.x; i < total; i += gridDim.x * 256) {
    if (i < nWtL) {
      int kt = i / WTILE;
      int rem = i - kt * WTILE;
      int g = rem / WSLAB;            // 0..17 (17 = chunk pad zone)
      int t = rem - g * WSLAB;
      float v = 0.f;
      if (g < 17 && t < 512) {
        int k = t >> 4, j = t & 15;
        int d = kt * GBK + k;
        v = (g < 16) ? Wp[(g * 16 + j) * DD + d] : down_val(j, d, Wd0, Wd1, Wd2, Wd3);
      }
      WtL[i] = v;
    } else if (i < nWtL + nWb) {
      int j = i - nWtL;
      int o = j / KE, c = j - o * KE;
      float v = 0.f;
      if (c < 1024) v = W[o * DD + c];
      else if (c == 1024) v = Wu0[o];
      else if (c < 1027) v = Wu1[o * 2 + (c - 1025)];
      else if (c < 1031) v = Wu2[o * 4 + (c - 1027)];
      else if (c < 1039) v = Wu3[o * 8 + (c - 1031)];
      Bx[j] = f2bf(v);
    } else {
      int j = i - nWtL - nWb;
      int row = j >> 4, c = j & 15;
      Ax[row * KE + 1040 + c] = 0;
    }
  }
}

// ---------------- kernel 1: fused gate GEMM + softmax/top1 + x->bf16 ----------------
// 512 threads (8 waves, 2/SIMD), 64 rows/block, R=2 rows x (16 proj + 1 down) per thread.
// W staged via wave-uniform global_load_lds chunks; x reg-staged (emits Ax bf16).
__global__ __launch_bounds__(512, 2) void gate_gemm4(
    const float* __restrict__ x, const float* __restrict__ WtL,
    const float* __restrict__ bp, const float* __restrict__ simn,
    const float* __restrict__ temp, unsigned short* __restrict__ Ax) {
  __shared__ __align__(16) float lds[2][BUFSZ];
  const int tid = threadIdx.x;
  const int lane = tid & 63, wv = tid >> 6;
  const int tr = tid >> 4;          // 0..31 -> rows 2tr, 2tr+1
  const int tc = tid & 15;          // proj col group (16 cols) + down col tc
  const int r0 = blockIdx.x * GROWS;
  const int sxr = tid >> 3;         // x stage: row 0..63
  const int sxc = (tid & 7) * 4;    // x stage: col quad within 32-k chunk
  const float* xg = &x[(r0 + sxr) * DD + sxc];
  unsigned short* axg = &Ax[(r0 + sxr) * KE + sxc];

  float acc[2][16] = {};
  float accd[2] = {};

  // ---- prologue: stage kt=0 into buf 0 ----
  {
    for (int cc = wv; cc < WCHUNK; cc += 8)   // wave-uniform chunk id
      gload16f(&WtL[cc * 256 + lane * 4], &lds[0][XTILE + cc * 256]);
    float4 xv = *(const float4*)xg;
    float* d = &lds[0][0];
    d[(sxc + 0) * XSTR + sxr] = xv.x;
    d[(sxc + 1) * XSTR + sxr] = xv.y;
    d[(sxc + 2) * XSTR + sxr] = xv.z;
    d[(sxc + 3) * XSTR + sxr] = xv.w;
    union { unsigned short s[4]; uint2 q; } pk;
    pk.s[0] = f2bf(xv.x); pk.s[1] = f2bf(xv.y); pk.s[2] = f2bf(xv.z); pk.s[3] = f2bf(xv.w);
    *reinterpret_cast<uint2*>(axg) = pk.q;
  }
  __syncthreads();

  int cur = 0;
  for (int kt = 0; kt < 32; ++kt) {
    float4 xn;
    if (kt < 31) {
      const float* wsrc = &WtL[(kt + 1) * WTILE];
      float* wdst = &lds[cur ^ 1][XTILE];
      for (int cc = wv; cc < WCHUNK; cc += 8)
        gload16f(wsrc + cc * 256 + lane * 4, wdst + cc * 256);
      xn = *(const float4*)(xg + (kt + 1) * GBK);
    }
    // ---- compute on lds[cur] ----
    const float* xs = &lds[cur][0];
    const float* ww = &lds[cur][XTILE];
#pragma unroll 4
    for (int k = 0; k < GBK; ++k) {
      float2 xa = *(const float2*)&xs[k * XSTR + tr * 2];
      const float* wp = &ww[tc * WSLAB + k * 16];
      float4 w0 = *(const float4*)(wp);
      float4 w1 = *(const float4*)(wp + 4);
      float4 w2 = *(const float4*)(wp + 8);
      float4 w3 = *(const float4*)(wp + 12);
      float wd = ww[16 * WSLAB + k * 16 + tc];
      float wv16[16] = {w0.x, w0.y, w0.z, w0.w, w1.x, w1.y, w1.z, w1.w,
                        w2.x, w2.y, w2.z, w2.w, w3.x, w3.y, w3.z, w3.w};
#pragma unroll
      for (int j = 0; j < 16; ++j) {
        acc[0][j] = __builtin_fmaf(xa.x, wv16[j], acc[0][j]);
        acc[1][j] = __builtin_fmaf(xa.y, wv16[j], acc[1][j]);
      }
      accd[0] = __builtin_fmaf(xa.x, wd, accd[0]);
      accd[1] = __builtin_fmaf(xa.y, wd, accd[1]);
    }
    if (kt < 31) {
      float* d = &lds[cur ^ 1][0];
      float xv4[4] = {xn.x, xn.y, xn.z, xn.w};
#pragma unroll
      for (int j = 0; j < 4; ++j)
        d[(sxc + j) * XSTR + sxr] = xv4[j];
      union { unsigned short s[4]; uint2 q; } pk;
#pragma unroll
      for (int j = 0; j < 4; ++j) pk.s[j] = f2bf(xv4[j]);
      *reinterpret_cast<uint2*>(axg + (kt + 1) * GBK) = pk.q;
      __syncthreads();   // drains gload16 (vmcnt) + lds writes, flips buffer
      cur ^= 1;
    }
  }

  // ---- fused finalize: bias, norm, logits, softmax-top1, scaled down cols ----
  const float scale = expf(fminf(temp[0], CLAMPV));
  float bj[16];
  {
    const float4* bpv = (const float4*)&bp[tc * 16];
    float4 b0 = bpv[0], b1 = bpv[1], b2 = bpv[2], b3 = bpv[3];
    bj[0]=b0.x; bj[1]=b0.y; bj[2]=b0.z; bj[3]=b0.w;
    bj[4]=b1.x; bj[5]=b1.y; bj[6]=b1.z; bj[7]=b1.w;
    bj[8]=b2.x; bj[9]=b2.y; bj[10]=b2.z; bj[11]=b2.w;
    bj[12]=b3.x; bj[13]=b3.y; bj[14]=b3.z; bj[15]=b3.w;
  }
  float ssq[2] = {};
  float ldv[2][4] = {};
#pragma unroll
  for (int j = 0; j < 16; ++j) {
    float4 sv = *(const float4*)&simn[(tc * 16 + j) * 4];
#pragma unroll
    for (int i = 0; i < 2; ++i) {
      float a = acc[i][j] + bj[j];
      ssq[i] += a * a;
      ldv[i][0] = __builtin_fmaf(a, sv.x, ldv[i][0]);
      ldv[i][1] = __builtin_fmaf(a, sv.y, ldv[i][1]);
      ldv[i][2] = __builtin_fmaf(a, sv.z, ldv[i][2]);
      ldv[i][3] = __builtin_fmaf(a, sv.w, ldv[i][3]);
    }
  }
  // butterfly reduce across the 16 tc lanes (stays within 16-lane groups)
#pragma unroll
  for (int off = 1; off < 16; off <<= 1) {
#pragma unroll
    for (int i = 0; i < 2; ++i) {
      ssq[i] += __shfl_xor(ssq[i], off, 64);
#pragma unroll
      for (int e = 0; e < 4; ++e) ldv[i][e] += __shfl_xor(ldv[i][e], off, 64);
    }
  }
#pragma unroll
  for (int i = 0; i < 2; ++i) {
    float inv = scale / fmaxf(sqrtf(ssq[i]), 1e-12f);
    float l[4];
#pragma unroll
    for (int e = 0; e < 4; ++e) l[e] = ldv[i][e] * inv;
    int be = 0; float m = l[0];
    if (l[1] > m) { m = l[1]; be = 1; }
    if (l[2] > m) { m = l[2]; be = 2; }
    if (l[3] > m) { m = l[3]; be = 3; }
    float den = expf(l[0]-m) + expf(l[1]-m) + expf(l[2]-m) + expf(l[3]-m);
    float g = 1.0f / den;
    int off = (1 << be) - 1;   // {0,1,3,7}
    int rr = 1 << be;          // {1,2,4,8}
    float v = (tc >= off && tc < off + rr) ? g * accd[i] : 0.f;
    Ax[(r0 + tr * 2 + i) * KE + 1024 + tc] = f2bf(v);
  }
}

// ---------------- kernel 2: bf16 MFMA GEMM C[16384,1024] = A[16384,1056] @ B[1024,1056]^T ----------------
__global__ __launch_bounds__(256) void main_gemm(
    const unsigned short* __restrict__ A, const unsigned short* __restrict__ Bm,
    float* __restrict__ C) {
  __shared__ __align__(16) unsigned short as_[2][128 * 32];
  __shared__ __align__(16) unsigned short bs_[2][128 * 32];
  const int tid = threadIdx.x;
  const int lane = tid & 63, wv = tid >> 6;
  const int wm = wv >> 1, wn = wv & 1;
  const int r0 = blockIdx.y * 128, c0 = blockIdx.x * 128;
  f32x4 acc[4][4] = {};
  const int se = wv * 512 + lane * 8;
  const int sr = se >> 5, sc = se & 31;
  const unsigned short* ga0 = &A[(r0 + sr) * KE + sc];
  const unsigned short* gb0 = &Bm[(c0 + sr) * KE + sc];
  gload16(ga0, &as_[0][wv * 512]);
  gload16(ga0 + 64 * KE, &as_[0][2048 + wv * 512]);
  gload16(gb0, &bs_[0][wv * 512]);
  gload16(gb0 + 64 * KE, &bs_[0][2048 + wv * 512]);
  const int ro = lane & 15, ko = (lane >> 4) * 8;
  int cur = 0;
  for (int kt = 0; kt < 33; ++kt) {
    __syncthreads();
    if (kt + 1 < 33) {
      const unsigned short* ga = ga0 + (kt + 1) * 32;
      const unsigned short* gb = gb0 + (kt + 1) * 32;
      int nb = cur ^ 1;
      gload16(ga, &as_[nb][wv * 512]);
      gload16(ga + 64 * KE, &as_[nb][2048 + wv * 512]);
      gload16(gb, &bs_[nb][wv * 512]);
      gload16(gb + 64 * KE, &bs_[nb][2048 + wv * 512]);
    }
    const unsigned short* ap = &as_[cur][0];
    const unsigned short* bpp = &bs_[cur][0];
    short8 af[4], bf[4];
#pragma unroll
    for (int m = 0; m < 4; ++m)
      af[m] = *reinterpret_cast<const short8*>(ap + (wm * 64 + m * 16 + ro) * 32 + ko);
#pragma unroll
    for (int n = 0; n < 4; ++n)
      bf[n] = *reinterpret_cast<const short8*>(bpp + (wn * 64 + n * 16 + ro) * 32 + ko);
#pragma unroll
    for (int m = 0; m < 4; ++m)
#pragma unroll
      for (int n = 0; n < 4; ++n)
        acc[m][n] = __builtin_amdgcn_mfma_f32_16x16x32_bf16(af[m], bf[n], acc[m][n], 0, 0, 0);
    cur ^= 1;
  }
#pragma unroll
  for (int m = 0; m < 4; ++m) {
    int rr = r0 + wm * 64 + m * 16 + (lane >> 4) * 4;
#pragma unroll
    for (int n = 0; n < 4; ++n) {
      int cc = c0 + wn * 64 + n * 16 + (lane & 15);
#pragma unroll
      for (int v = 0; v < 4; ++v)
        C[(rr + v) * OO + cc] = acc[m][n][v];
    }
  }
}

extern "C" void kernel_launch(void* const* d_in, const int* in_sizes, int n_in,
                              void* d_out, int out_size, void* d_ws, size_t ws_size,
                              hipStream_t stream) {
  const float* x    = (const float*)d_in[0];
  const float* W    = (const float*)d_in[1];
  const float* Wp   = (const float*)d_in[2];
  const float* bp   = (const float*)d_in[3];
  const float* sim  = (const float*)d_in[4];
  const float* temp = (const float*)d_in[5];
  const float* Wd0  = (const float*)d_in[6];
  const float* Wu0  = (const float*)d_in[7];
  const float* Wd1  = (const float*)d_in[8];
  const float* Wu1  = (const float*)d_in[9];
  const float* Wd2  = (const float*)d_in[10];
  const float* Wu2  = (const float*)d_in[11];
  const float* Wd3  = (const float*)d_in[12];
  const float* Wu3  = (const float*)d_in[13];
  float* out = (float*)d_out;
  char* ws = (char*)d_ws;
  // ws layout (total 37,949,440 B):
  unsigned short* Ax  = (unsigned short*)ws;                 // [16384][1056] bf16 = 34,603,008
  unsigned short* Bx  = (unsigned short*)(ws + 34603008);    // [1024][1056] bf16 =  2,162,688
  float* WtL          = (float*)(ws + 36765696);             // [32][9216] f32    =  1,179,648
  float* simn         = (float*)(ws + 37945344);             // [256][4] f32      =      4,096

  prep2<<<1024, 256, 0, stream>>>(W, Wp, sim, Wd0, Wd1, Wd2, Wd3,
                                  Wu0, Wu1, Wu2, Wu3, WtL, Bx, Ax, simn);
  gate_gemm4<<<256, 512, 0, stream>>>(x, WtL, bp, simn, temp, Ax);
  main_gemm<<<dim3(8, 128), 256, 0, stream>>>(Ax, Bx, out);
}

// Round 5
// 217.212 us; speedup vs baseline: 1.0891x; 1.0891x over previous
//
#include <hip/hip_runtime.h>

#define TOK 16384
#define DD 1024
#define OO 1024
#define KE 1056     // 1024 + 16 lora cols + 16 pad
#define CLAMPV 4.605170185988091f

// gate tiling
#define GROWS 64                // rows per gate block
#define GBK 32                  // K chunk per stage
#define WSLAB 260               // floats per 8-col slab (32k*8 + 4 pad); 260%32=4 -> min banking
#define WDOWN 8320              // 32*260: offset of down-col region [32k][16]
#define WTILE 8960              // 8320 + 512 + 128 pad = 35 chunks of 256 floats
#define WCHUNK 35               // 256-float wave-uniform chunks per kt tile
#define XSTR 68                 // x tile row stride (64 rows + 4 pad)
#define XTILE (GBK * XSTR)      // 2176 floats
#define BUFSZ (XTILE + WTILE)   // 11136 floats per buffer (44544 B)

typedef __attribute__((ext_vector_type(8))) short short8;
typedef __attribute__((ext_vector_type(4))) float f32x4;

__device__ __forceinline__ unsigned short f2bf(float f) {
  unsigned int u = __float_as_uint(f);
  return (unsigned short)((u + 0x7FFFu + ((u >> 16) & 1u)) >> 16);
}

__device__ __forceinline__ void gload16(const unsigned short* g, unsigned short* l) {
  __builtin_amdgcn_global_load_lds(
      (const __attribute__((address_space(1))) void*)g,
      (__attribute__((address_space(3))) void*)l, 16, 0, 0);
}

__device__ __forceinline__ void gload16f(const float* g, float* l) {
  __builtin_amdgcn_global_load_lds(
      (const __attribute__((address_space(1))) void*)g,
      (__attribute__((address_space(3))) void*)l, 16, 0, 0);
}

__device__ __forceinline__ float down_val(int j, int d,
    const float* __restrict__ Wd0, const float* __restrict__ Wd1,
    const float* __restrict__ Wd2, const float* __restrict__ Wd3) {
  if (j == 0) return Wd0[d];
  if (j < 3) return Wd1[(j - 1) * DD + d];
  if (j < 7) return Wd2[(j - 3) * DD + d];
  if (j < 15) return Wd3[(j - 7) * DD + d];
  return 0.f;
}

// ---------------- kernel 0: prep (WtL blocked fp32, Bx bf16, Ax pad, simn) ----------------
__global__ __launch_bounds__(256) void prep2(
    const float* __restrict__ W, const float* __restrict__ Wp,
    const float* __restrict__ sim,
    const float* __restrict__ Wd0, const float* __restrict__ Wd1,
    const float* __restrict__ Wd2, const float* __restrict__ Wd3,
    const float* __restrict__ Wu0, const float* __restrict__ Wu1,
    const float* __restrict__ Wu2, const float* __restrict__ Wu3,
    float* __restrict__ WtL, unsigned short* __restrict__ Bx,
    unsigned short* __restrict__ Ax, float* __restrict__ simn) {
  __shared__ float part[4][4];
  if (blockIdx.x == 0) {
    // simn = sim / ||sim col||  (sim is [256][4] row-major)
    int t = threadIdx.x;
    float4 sv = *(const float4*)&sim[t * 4];
    float v[4] = {sv.x * sv.x, sv.y * sv.y, sv.z * sv.z, sv.w * sv.w};
#pragma unroll
    for (int off = 1; off < 64; off <<= 1) {
#pragma unroll
      for (int e = 0; e < 4; ++e) v[e] += __shfl_xor(v[e], off, 64);
    }
    int wv = t >> 6, ln = t & 63;
    if (ln == 0) { part[wv][0] = v[0]; part[wv][1] = v[1]; part[wv][2] = v[2]; part[wv][3] = v[3]; }
    __syncthreads();
    float4 o;
    o.x = sv.x / fmaxf(sqrtf(part[0][0] + part[1][0] + part[2][0] + part[3][0]), 1e-12f);
    o.y = sv.y / fmaxf(sqrtf(part[0][1] + part[1][1] + part[2][1] + part[3][1]), 1e-12f);
    o.z = sv.z / fmaxf(sqrtf(part[0][2] + part[1][2] + part[2][2] + part[3][2]), 1e-12f);
    o.w = sv.w / fmaxf(sqrtf(part[0][3] + part[1][3] + part[2][3] + part[3][3]), 1e-12f);
    *(float4*)&simn[t * 4] = o;
  }
  const int nWtL = 32 * WTILE;      // 286720
  const int nWb = OO * KE;          // 1081344
  const int nXpad = TOK * 16;       // 262144
  const int total = nWtL + nWb + nXpad;
  for (int i = blockIdx.x * 256 + threadIdx.x; i < total; i += gridDim.x * 256) {
    if (i < nWtL) {
      int kt = i / WTILE;
      int rem = i - kt * WTILE;
      float v = 0.f;
      if (rem < WDOWN) {
        int g = rem / WSLAB, t = rem - g * WSLAB;
        if (t < 256) {
          int k = t >> 3, c = t & 7;
          v = Wp[(g * 8 + c) * DD + kt * GBK + k];
        }
      } else if (rem < WDOWN + 512) {
        int t = rem - WDOWN;
        int k = t >> 4, j = t & 15;
        v = down_val(j, kt * GBK + k, Wd0, Wd1, Wd2, Wd3);
      }
      WtL[i] = v;
    } else if (i < nWtL + nWb) {
      int j = i - nWtL;
      int o = j / KE, c = j - o * KE;
      float v = 0.f;
      if (c < 1024) v = W[o * DD + c];
      else if (c == 1024) v = Wu0[o];
      else if (c < 1027) v = Wu1[o * 2 + (c - 1025)];
      else if (c < 1031) v = Wu2[o * 4 + (c - 1027)];
      else if (c < 1039) v = Wu3[o * 8 + (c - 1031)];
      Bx[j] = f2bf(v);
    } else {
      int j = i - nWtL - nWb;
      int row = j >> 4, c = j & 15;
      Ax[row * KE + 1040 + c] = 0;
    }
  }
}

// ---------------- kernel 1: fused gate GEMM + softmax/top1 + x->bf16 ----------------
// 512 threads (8 waves, 2/SIMD), 64 rows/block.
// R=4 rows (tr=tid>>5) x C=8 proj cols (tc=tid&31) + 1 down col (tc<16) per thread.
// Per k: 1 b128 x + 2 b128 W + 1 b32 wd = 4 DS instrs for 36 FMAs.
__global__ __launch_bounds__(512, 2) void gate_gemm5(
    const float* __restrict__ x, const float* __restrict__ WtL,
    const float* __restrict__ bp, const float* __restrict__ simn,
    const float* __restrict__ temp, unsigned short* __restrict__ Ax) {
  __shared__ __align__(16) float lds[2][BUFSZ];
  const int tid = threadIdx.x;
  const int lane = tid & 63, wv = tid >> 6;
  const int tr = tid >> 5;          // 0..15 -> rows 4tr..4tr+3
  const int tc = tid & 31;          // 8 proj cols tc*8..+7; down col tc (tc<16)
  const int r0 = blockIdx.x * GROWS;
  const int sxr = tid >> 3;         // x stage: row 0..63
  const int sxc = (tid & 7) * 4;    // x stage: col quad within 32-k chunk
  const float* xg = &x[(r0 + sxr) * DD + sxc];
  unsigned short* axg = &Ax[(r0 + sxr) * KE + sxc];

  float acc[4][8] = {};
  float accd[4] = {};

  // ---- prologue: stage kt=0 into buf 0 ----
  {
    for (int cc = wv; cc < WCHUNK; cc += 8)   // wave-uniform chunk id
      gload16f(&WtL[cc * 256 + lane * 4], &lds[0][XTILE + cc * 256]);
    float4 xv = *(const float4*)xg;
    float* d = &lds[0][0];
    d[(sxc + 0) * XSTR + sxr] = xv.x;
    d[(sxc + 1) * XSTR + sxr] = xv.y;
    d[(sxc + 2) * XSTR + sxr] = xv.z;
    d[(sxc + 3) * XSTR + sxr] = xv.w;
    union { unsigned short s[4]; uint2 q; } pk;
    pk.s[0] = f2bf(xv.x); pk.s[1] = f2bf(xv.y); pk.s[2] = f2bf(xv.z); pk.s[3] = f2bf(xv.w);
    *reinterpret_cast<uint2*>(axg) = pk.q;
  }
  __syncthreads();

  int cur = 0;
  for (int kt = 0; kt < 32; ++kt) {
    float4 xn;
    if (kt < 31) {
      const float* wsrc = &WtL[(kt + 1) * WTILE];
      float* wdst = &lds[cur ^ 1][XTILE];
      for (int cc = wv; cc < WCHUNK; cc += 8)
        gload16f(wsrc + cc * 256 + lane * 4, wdst + cc * 256);
      xn = *(const float4*)(xg + (kt + 1) * GBK);
    }
    // ---- compute on lds[cur] ----
    const float* xs = &lds[cur][0];
    const float* ww = &lds[cur][XTILE];
#pragma unroll 4
    for (int k = 0; k < GBK; ++k) {
      float4 xa = *(const float4*)&xs[k * XSTR + tr * 4];
      const float* wp = &ww[tc * WSLAB + k * 8];
      float4 w0 = *(const float4*)(wp);
      float4 w1 = *(const float4*)(wp + 4);
      float wd = ww[WDOWN + k * 16 + (tc & 15)];
      float xa4[4] = {xa.x, xa.y, xa.z, xa.w};
      float wv8[8] = {w0.x, w0.y, w0.z, w0.w, w1.x, w1.y, w1.z, w1.w};
#pragma unroll
      for (int i = 0; i < 4; ++i) {
#pragma unroll
        for (int j = 0; j < 8; ++j)
          acc[i][j] = __builtin_fmaf(xa4[i], wv8[j], acc[i][j]);
        accd[i] = __builtin_fmaf(xa4[i], wd, accd[i]);
      }
    }
    if (kt < 31) {
      float* d = &lds[cur ^ 1][0];
      float xv4[4] = {xn.x, xn.y, xn.z, xn.w};
#pragma unroll
      for (int j = 0; j < 4; ++j)
        d[(sxc + j) * XSTR + sxr] = xv4[j];
      union { unsigned short s[4]; uint2 q; } pk;
#pragma unroll
      for (int j = 0; j < 4; ++j) pk.s[j] = f2bf(xv4[j]);
      *reinterpret_cast<uint2*>(axg + (kt + 1) * GBK) = pk.q;
      __syncthreads();   // drains gload16 (vmcnt) + lds writes, flips buffer
      cur ^= 1;
    }
  }

  // ---- fused finalize: bias, norm, logits, softmax-top1, scaled down cols ----
  const float scale = expf(fminf(temp[0], CLAMPV));
  float bj[8];
  {
    const float4* bpv = (const float4*)&bp[tc * 8];
    float4 b0 = bpv[0], b1 = bpv[1];
    bj[0]=b0.x; bj[1]=b0.y; bj[2]=b0.z; bj[3]=b0.w;
    bj[4]=b1.x; bj[5]=b1.y; bj[6]=b1.z; bj[7]=b1.w;
  }
  float ssq[4] = {};
  float ldv[4][4] = {};
#pragma unroll
  for (int j = 0; j < 8; ++j) {
    float4 sv = *(const float4*)&simn[(tc * 8 + j) * 4];
#pragma unroll
    for (int i = 0; i < 4; ++i) {
      float a = acc[i][j] + bj[j];
      ssq[i] += a * a;
      ldv[i][0] = __builtin_fmaf(a, sv.x, ldv[i][0]);
      ldv[i][1] = __builtin_fmaf(a, sv.y, ldv[i][1]);
      ldv[i][2] = __builtin_fmaf(a, sv.z, ldv[i][2]);
      ldv[i][3] = __builtin_fmaf(a, sv.w, ldv[i][3]);
    }
  }
  // butterfly reduce across the 32 tc lanes (lane bits 0..4, stays within wave halves)
#pragma unroll
  for (int off = 1; off < 32; off <<= 1) {
#pragma unroll
    for (int i = 0; i < 4; ++i) {
      ssq[i] += __shfl_xor(ssq[i], off, 64);
#pragma unroll
      for (int e = 0; e < 4; ++e) ldv[i][e] += __shfl_xor(ldv[i][e], off, 64);
    }
  }
#pragma unroll
  for (int i = 0; i < 4; ++i) {
    float inv = scale / fmaxf(sqrtf(ssq[i]), 1e-12f);
    float l[4];
#pragma unroll
    for (int e = 0; e < 4; ++e) l[e] = ldv[i][e] * inv;
    int be = 0; float m = l[0];
    if (l[1] > m) { m = l[1]; be = 1; }
    if (l[2] > m) { m = l[2]; be = 2; }
    if (l[3] > m) { m = l[3]; be = 3; }
    float den = expf(l[0]-m) + expf(l[1]-m) + expf(l[2]-m) + expf(l[3]-m);
    float g = 1.0f / den;
    int off = (1 << be) - 1;   // {0,1,3,7}
    int rr = 1 << be;          // {1,2,4,8}
    if (tc < 16) {
      float v = (tc >= off && tc < off + rr) ? g * accd[i] : 0.f;
      Ax[(r0 + tr * 4 + i) * KE + 1024 + tc] = f2bf(v);
    }
  }
}

// ---------------- kernel 2: bf16 MFMA GEMM C[16384,1024] = A[16384,1056] @ B[1024,1056]^T ----------------
__global__ __launch_bounds__(256) void main_gemm(
    const unsigned short* __restrict__ A, const unsigned short* __restrict__ Bm,
    float* __restrict__ C) {
  __shared__ __align__(16) unsigned short as_[2][128 * 32];
  __shared__ __align__(16) unsigned short bs_[2][128 * 32];
  const int tid = threadIdx.x;
  const int lane = tid & 63, wv = tid >> 6;
  const int wm = wv >> 1, wn = wv & 1;
  const int r0 = blockIdx.y * 128, c0 = blockIdx.x * 128;
  f32x4 acc[4][4] = {};
  const int se = wv * 512 + lane * 8;
  const int sr = se >> 5, sc = se & 31;
  const unsigned short* ga0 = &A[(r0 + sr) * KE + sc];
  const unsigned short* gb0 = &Bm[(c0 + sr) * KE + sc];
  gload16(ga0, &as_[0][wv * 512]);
  gload16(ga0 + 64 * KE, &as_[0][2048 + wv * 512]);
  gload16(gb0, &bs_[0][wv * 512]);
  gload16(gb0 + 64 * KE, &bs_[0][2048 + wv * 512]);
  const int ro = lane & 15, ko = (lane >> 4) * 8;
  int cur = 0;
  for (int kt = 0; kt < 33; ++kt) {
    __syncthreads();
    if (kt + 1 < 33) {
      const unsigned short* ga = ga0 + (kt + 1) * 32;
      const unsigned short* gb = gb0 + (kt + 1) * 32;
      int nb = cur ^ 1;
      gload16(ga, &as_[nb][wv * 512]);
      gload16(ga + 64 * KE, &as_[nb][2048 + wv * 512]);
      gload16(gb, &bs_[nb][wv * 512]);
      gload16(gb + 64 * KE, &bs_[nb][2048 + wv * 512]);
    }
    const unsigned short* ap = &as_[cur][0];
    const unsigned short* bpp = &bs_[cur][0];
    short8 af[4], bf[4];
#pragma unroll
    for (int m = 0; m < 4; ++m)
      af[m] = *reinterpret_cast<const short8*>(ap + (wm * 64 + m * 16 + ro) * 32 + ko);
#pragma unroll
    for (int n = 0; n < 4; ++n)
      bf[n] = *reinterpret_cast<const short8*>(bpp + (wn * 64 + n * 16 + ro) * 32 + ko);
#pragma unroll
    for (int m = 0; m < 4; ++m)
#pragma unroll
      for (int n = 0; n < 4; ++n)
        acc[m][n] = __builtin_amdgcn_mfma_f32_16x16x32_bf16(af[m], bf[n], acc[m][n], 0, 0, 0);
    cur ^= 1;
  }
#pragma unroll
  for (int m = 0; m < 4; ++m) {
    int rr = r0 + wm * 64 + m * 16 + (lane >> 4) * 4;
#pragma unroll
    for (int n = 0; n < 4; ++n) {
      int cc = c0 + wn * 64 + n * 16 + (lane & 15);
#pragma unroll
      for (int v = 0; v < 4; ++v)
        C[(rr + v) * OO + cc] = acc[m][n][v];
    }
  }
}

extern "C" void kernel_launch(void* const* d_in, const int* in_sizes, int n_in,
                              void* d_out, int out_size, void* d_ws, size_t ws_size,
                              hipStream_t stream) {
  const float* x    = (const float*)d_in[0];
  const float* W    = (const float*)d_in[1];
  const float* Wp   = (const float*)d_in[2];
  const float* bp   = (const float*)d_in[3];
  const float* sim  = (const float*)d_in[4];
  const float* temp = (const float*)d_in[5];
  const float* Wd0  = (const float*)d_in[6];
  const float* Wu0  = (const float*)d_in[7];
  const float* Wd1  = (const float*)d_in[8];
  const float* Wu1  = (const float*)d_in[9];
  const float* Wd2  = (const float*)d_in[10];
  const float* Wu2  = (const float*)d_in[11];
  const float* Wd3  = (const float*)d_in[12];
  const float* Wu3  = (const float*)d_in[13];
  float* out = (float*)d_out;
  char* ws = (char*)d_ws;
  // ws layout (total 37,916,672 B):
  unsigned short* Ax  = (unsigned short*)ws;                 // [16384][1056] bf16 = 34,603,008
  unsigned short* Bx  = (unsigned short*)(ws + 34603008);    // [1024][1056] bf16 =  2,162,688
  float* WtL          = (float*)(ws + 36765696);             // [32][8960] f32    =  1,146,880
  float* simn         = (float*)(ws + 37912576);             // [256][4] f32      =      4,096

  prep2<<<1024, 256, 0, stream>>>(W, Wp, sim, Wd0, Wd1, Wd2, Wd3,
                                  Wu0, Wu1, Wu2, Wu3, WtL, Bx, Ax, simn);
  gate_gemm5<<<256, 512, 0, stream>>>(x, WtL, bp, simn, temp, Ax);
  main_gemm<<<dim3(8, 128), 256, 0, stream>>>(Ax, Bx, out);
}

// Round 6
// 215.242 us; speedup vs baseline: 1.0991x; 1.0092x over previous
//
#include <hip/hip_runtime.h>

#define TOK 16384
#define DD 1024
#define OO 1024
#define KE 1056     // 1024 + 16 lora cols + 16 pad
#define CLAMPV 4.605170185988091f

// gate tiling
#define GROWS 64                // rows per gate block
#define GBK 32                  // K chunk per stage
#define WROW 296                // floats per k-row (256 proj + 16 down + 24 pad)
#define WTILE 9472              // 32 * 296 = 37 chunks of 256 floats (exact)
#define WCHUNK 37               // 256-float wave-uniform chunks per kt tile
#define XSTR 68                 // x tile row stride (64 rows + 4 pad)
#define XTILE (GBK * XSTR)      // 2176 floats
#define BUFSZ (XTILE + WTILE)   // 11648 floats per buffer (46592 B)

typedef __attribute__((ext_vector_type(8))) short short8;
typedef __attribute__((ext_vector_type(4))) float f32x4;

__device__ __forceinline__ unsigned short f2bf(float f) {
  unsigned int u = __float_as_uint(f);
  return (unsigned short)((u + 0x7FFFu + ((u >> 16) & 1u)) >> 16);
}

__device__ __forceinline__ void gload16(const unsigned short* g, unsigned short* l) {
  __builtin_amdgcn_global_load_lds(
      (const __attribute__((address_space(1))) void*)g,
      (__attribute__((address_space(3))) void*)l, 16, 0, 0);
}

__device__ __forceinline__ void gload16f(const float* g, float* l) {
  __builtin_amdgcn_global_load_lds(
      (const __attribute__((address_space(1))) void*)g,
      (__attribute__((address_space(3))) void*)l, 16, 0, 0);
}

__device__ __forceinline__ float down_val(int j, int d,
    const float* __restrict__ Wd0, const float* __restrict__ Wd1,
    const float* __restrict__ Wd2, const float* __restrict__ Wd3) {
  if (j == 0) return Wd0[d];
  if (j < 3) return Wd1[(j - 1) * DD + d];
  if (j < 7) return Wd2[(j - 3) * DD + d];
  if (j < 15) return Wd3[(j - 7) * DD + d];
  return 0.f;
}

// ---------------- kernel 0: prep (WtL blocked fp32, Bx bf16, Ax pad, simn) ----------------
__global__ __launch_bounds__(256) void prep2(
    const float* __restrict__ W, const float* __restrict__ Wp,
    const float* __restrict__ sim,
    const float* __restrict__ Wd0, const float* __restrict__ Wd1,
    const float* __restrict__ Wd2, const float* __restrict__ Wd3,
    const float* __restrict__ Wu0, const float* __restrict__ Wu1,
    const float* __restrict__ Wu2, const float* __restrict__ Wu3,
    float* __restrict__ WtL, unsigned short* __restrict__ Bx,
    unsigned short* __restrict__ Ax, float* __restrict__ simn) {
  __shared__ float part[4][4];
  if (blockIdx.x == 0) {
    // simn = sim / ||sim col||  (sim is [256][4] row-major)
    int t = threadIdx.x;
    float4 sv = *(const float4*)&sim[t * 4];
    float v[4] = {sv.x * sv.x, sv.y * sv.y, sv.z * sv.z, sv.w * sv.w};
#pragma unroll
    for (int off = 1; off < 64; off <<= 1) {
#pragma unroll
      for (int e = 0; e < 4; ++e) v[e] += __shfl_xor(v[e], off, 64);
    }
    int wv = t >> 6, ln = t & 63;
    if (ln == 0) { part[wv][0] = v[0]; part[wv][1] = v[1]; part[wv][2] = v[2]; part[wv][3] = v[3]; }
    __syncthreads();
    float4 o;
    o.x = sv.x / fmaxf(sqrtf(part[0][0] + part[1][0] + part[2][0] + part[3][0]), 1e-12f);
    o.y = sv.y / fmaxf(sqrtf(part[0][1] + part[1][1] + part[2][1] + part[3][1]), 1e-12f);
    o.z = sv.z / fmaxf(sqrtf(part[0][2] + part[1][2] + part[2][2] + part[3][2]), 1e-12f);
    o.w = sv.w / fmaxf(sqrtf(part[0][3] + part[1][3] + part[2][3] + part[3][3]), 1e-12f);
    *(float4*)&simn[t * 4] = o;
  }
  const int nWtL = 32 * WTILE;      // 303104
  const int nWb = OO * KE;          // 1081344
  const int nXpad = TOK * 16;       // 262144
  const int total = nWtL + nWb + nXpad;
  for (int i = blockIdx.x * 256 + threadIdx.x; i < total; i += gridDim.x * 256) {
    if (i < nWtL) {
      int kt = i / WTILE;
      int rem = i - kt * WTILE;
      int k = rem / WROW;
      int c = rem - k * WROW;
      float v = 0.f;
      int d = kt * GBK + k;
      if (c < 256) v = Wp[c * DD + d];
      else if (c < 272) v = down_val(c - 256, d, Wd0, Wd1, Wd2, Wd3);
      WtL[i] = v;
    } else if (i < nWtL + nWb) {
      int j = i - nWtL;
      int o = j / KE, c = j - o * KE;
      float v = 0.f;
      if (c < 1024) v = W[o * DD + c];
      else if (c == 1024) v = Wu0[o];
      else if (c < 1027) v = Wu1[o * 2 + (c - 1025)];
      else if (c < 1031) v = Wu2[o * 4 + (c - 1027)];
      else if (c < 1039) v = Wu3[o * 8 + (c - 1031)];
      Bx[j] = f2bf(v);
    } else {
      int j = i - nWtL - nWb;
      int row = j >> 4, c = j & 15;
      Ax[row * KE + 1040 + c] = 0;
    }
  }
}

// ---------------- kernel 1: fused gate GEMM + softmax/top1 + x->bf16 ----------------
// 512 threads (8 waves, 2/SIMD), 64 rows/block.
// Wave = (row-half h, col-quarter q): 32 rows x 64 proj cols (+8 down cols).
// Thread: rg=lane>>3 -> 4 rows; cg=lane&7 -> 8 proj cols + 1 down col.
// Per k: 1 b128 x (8 uniq) + 2 b128 W (8 uniq) + 1 b32 wd (8 uniq) -> ~6 bank cyc.
__global__ __launch_bounds__(512, 2) void gate_gemm6(
    const float* __restrict__ x, const float* __restrict__ WtL,
    const float* __restrict__ bp, const float* __restrict__ simn,
    const float* __restrict__ temp, unsigned short* __restrict__ Ax) {
  __shared__ __align__(16) float lds[2][BUFSZ];
  const int tid = threadIdx.x;
  const int lane = tid & 63, wv = tid >> 6;
  const int h = wv & 1, q = wv >> 1;
  const int rg = lane >> 3, cg = lane & 7;
  const int rbase = h * 32 + rg * 4;     // 4 rows (within 64-row block)
  const int cbase = q * 64 + cg * 8;     // 8 proj cols
  const int dcol = (q & 1) * 8 + cg;     // 1 down col
  const int r0 = blockIdx.x * GROWS;
  const int sxr = tid >> 3;              // x stage: row 0..63
  const int sxc = (tid & 7) * 4;         // x stage: col quad within 32-k chunk
  const float* xg = &x[(r0 + sxr) * DD + sxc];
  unsigned short* axg = &Ax[(r0 + sxr) * KE + sxc];

  float acc[4][8] = {};
  float accd[4] = {};

  // ---- prologue: stage kt=0 into buf 0 ----
  {
    for (int cc = wv; cc < WCHUNK; cc += 8)   // wave-uniform chunk id
      gload16f(&WtL[cc * 256 + lane * 4], &lds[0][XTILE + cc * 256]);
    float4 xv = *(const float4*)xg;
    float* d = &lds[0][0];
    d[(sxc + 0) * XSTR + sxr] = xv.x;
    d[(sxc + 1) * XSTR + sxr] = xv.y;
    d[(sxc + 2) * XSTR + sxr] = xv.z;
    d[(sxc + 3) * XSTR + sxr] = xv.w;
    union { unsigned short s[4]; uint2 q2; } pk;
    pk.s[0] = f2bf(xv.x); pk.s[1] = f2bf(xv.y); pk.s[2] = f2bf(xv.z); pk.s[3] = f2bf(xv.w);
    *reinterpret_cast<uint2*>(axg) = pk.q2;
  }
  __syncthreads();

  int cur = 0;
  for (int kt = 0; kt < 32; ++kt) {
    float4 xn;
    if (kt < 31) {
      const float* wsrc = &WtL[(kt + 1) * WTILE];
      float* wdst = &lds[cur ^ 1][XTILE];
      for (int cc = wv; cc < WCHUNK; cc += 8)
        gload16f(wsrc + cc * 256 + lane * 4, wdst + cc * 256);
      xn = *(const float4*)(xg + (kt + 1) * GBK);
    }
    // ---- compute on lds[cur] ----
    const float* xs = &lds[cur][0];
    const float* ww = &lds[cur][XTILE];
#pragma unroll 4
    for (int k = 0; k < GBK; ++k) {
      float4 xa = *(const float4*)&xs[k * XSTR + rbase];
      const float* wp = &ww[k * WROW + cbase];
      float4 w0 = *(const float4*)(wp);
      float4 w1 = *(const float4*)(wp + 4);
      float wd = ww[k * WROW + 256 + dcol];
      float xa4[4] = {xa.x, xa.y, xa.z, xa.w};
      float wv8[8] = {w0.x, w0.y, w0.z, w0.w, w1.x, w1.y, w1.z, w1.w};
#pragma unroll
      for (int i = 0; i < 4; ++i) {
#pragma unroll
        for (int j = 0; j < 8; ++j)
          acc[i][j] = __builtin_fmaf(xa4[i], wv8[j], acc[i][j]);
        accd[i] = __builtin_fmaf(xa4[i], wd, accd[i]);
      }
    }
    if (kt < 31) {
      float* d = &lds[cur ^ 1][0];
      float xv4[4] = {xn.x, xn.y, xn.z, xn.w};
#pragma unroll
      for (int j = 0; j < 4; ++j)
        d[(sxc + j) * XSTR + sxr] = xv4[j];
      union { unsigned short s[4]; uint2 q2; } pk;
#pragma unroll
      for (int j = 0; j < 4; ++j) pk.s[j] = f2bf(xv4[j]);
      *reinterpret_cast<uint2*>(axg + (kt + 1) * GBK) = pk.q2;
      __syncthreads();   // drains gload16 (vmcnt) + lds writes, flips buffer
      cur ^= 1;
    }
  }

  // ---- per-quarter partials: bias, ssq, logit dots ----
  float ssq[4] = {};
  float ldv[4][4] = {};
  {
    float4 b0 = *(const float4*)&bp[cbase];
    float4 b1 = *(const float4*)&bp[cbase + 4];
    float bj[8] = {b0.x, b0.y, b0.z, b0.w, b1.x, b1.y, b1.z, b1.w};
#pragma unroll
    for (int j = 0; j < 8; ++j) {
      float4 sv = *(const float4*)&simn[(cbase + j) * 4];
#pragma unroll
      for (int i = 0; i < 4; ++i) {
        float a = acc[i][j] + bj[j];
        ssq[i] += a * a;
        ldv[i][0] = __builtin_fmaf(a, sv.x, ldv[i][0]);
        ldv[i][1] = __builtin_fmaf(a, sv.y, ldv[i][1]);
        ldv[i][2] = __builtin_fmaf(a, sv.z, ldv[i][2]);
        ldv[i][3] = __builtin_fmaf(a, sv.w, ldv[i][3]);
      }
    }
  }
  // butterfly over the 8 cg lanes (lane bits 0..2)
#pragma unroll
  for (int off = 1; off < 8; off <<= 1) {
#pragma unroll
    for (int i = 0; i < 4; ++i) {
      ssq[i] += __shfl_xor(ssq[i], off, 64);
#pragma unroll
      for (int e = 0; e < 4; ++e) ldv[i][e] += __shfl_xor(ldv[i][e], off, 64);
    }
  }
  // scratch in the non-final buffer: part[64 rows][4 quarters][5], down[64][16]
  float* part = &lds[cur ^ 1][0];
  float* down = &lds[cur ^ 1][64 * 20];
  if (cg == 0) {
#pragma unroll
    for (int i = 0; i < 4; ++i) {
      float* p = &part[(rbase + i) * 20 + q * 5];
      p[0] = ssq[i];
      p[1] = ldv[i][0]; p[2] = ldv[i][1]; p[3] = ldv[i][2]; p[4] = ldv[i][3];
    }
  }
  if (q < 2) {
#pragma unroll
    for (int i = 0; i < 4; ++i)
      down[(rbase + i) * 16 + dcol] = accd[i];
  }
  __syncthreads();

  // ---- finalize: one thread per row ----
  if (tid < GROWS) {
    const float scale = expf(fminf(temp[0], CLAMPV));
    float ssqT = 0.f, ld[4] = {};
#pragma unroll
    for (int qq = 0; qq < 4; ++qq) {
      const float* p = &part[tid * 20 + qq * 5];
      ssqT += p[0];
      ld[0] += p[1]; ld[1] += p[2]; ld[2] += p[3]; ld[3] += p[4];
    }
    float inv = scale / fmaxf(sqrtf(ssqT), 1e-12f);
    float l[4];
#pragma unroll
    for (int e = 0; e < 4; ++e) l[e] = ld[e] * inv;
    int be = 0; float m = l[0];
    if (l[1] > m) { m = l[1]; be = 1; }
    if (l[2] > m) { m = l[2]; be = 2; }
    if (l[3] > m) { m = l[3]; be = 3; }
    float den = expf(l[0]-m) + expf(l[1]-m) + expf(l[2]-m) + expf(l[3]-m);
    float g = 1.0f / den;
    int off = (1 << be) - 1;   // {0,1,3,7}
    int rr = 1 << be;          // {1,2,4,8}
    union { unsigned short s[16]; uint4 v[2]; } o;
#pragma unroll
    for (int j = 0; j < 16; ++j) {
      float dv = down[tid * 16 + j];
      float v = (j >= off && j < off + rr) ? g * dv : 0.f;
      o.s[j] = f2bf(v);
    }
    uint4* dst = reinterpret_cast<uint4*>(&Ax[(r0 + tid) * KE + 1024]);
    dst[0] = o.v[0];
    dst[1] = o.v[1];
  }
}

// ---------------- kernel 2: bf16 MFMA GEMM C[16384,1024] = A[16384,1056] @ B[1024,1056]^T ----------------
__global__ __launch_bounds__(256) void main_gemm(
    const unsigned short* __restrict__ A, const unsigned short* __restrict__ Bm,
    float* __restrict__ C) {
  __shared__ __align__(16) unsigned short as_[2][128 * 32];
  __shared__ __align__(16) unsigned short bs_[2][128 * 32];
  const int tid = threadIdx.x;
  const int lane = tid & 63, wv = tid >> 6;
  const int wm = wv >> 1, wn = wv & 1;
  const int r0 = blockIdx.y * 128, c0 = blockIdx.x * 128;
  f32x4 acc[4][4] = {};
  const int se = wv * 512 + lane * 8;
  const int sr = se >> 5, sc = se & 31;
  const unsigned short* ga0 = &A[(r0 + sr) * KE + sc];
  const unsigned short* gb0 = &Bm[(c0 + sr) * KE + sc];
  gload16(ga0, &as_[0][wv * 512]);
  gload16(ga0 + 64 * KE, &as_[0][2048 + wv * 512]);
  gload16(gb0, &bs_[0][wv * 512]);
  gload16(gb0 + 64 * KE, &bs_[0][2048 + wv * 512]);
  const int ro = lane & 15, ko = (lane >> 4) * 8;
  int cur = 0;
  for (int kt = 0; kt < 33; ++kt) {
    __syncthreads();
    if (kt + 1 < 33) {
      const unsigned short* ga = ga0 + (kt + 1) * 32;
      const unsigned short* gb = gb0 + (kt + 1) * 32;
      int nb = cur ^ 1;
      gload16(ga, &as_[nb][wv * 512]);
      gload16(ga + 64 * KE, &as_[nb][2048 + wv * 512]);
      gload16(gb, &bs_[nb][wv * 512]);
      gload16(gb + 64 * KE, &bs_[nb][2048 + wv * 512]);
    }
    const unsigned short* ap = &as_[cur][0];
    const unsigned short* bpp = &bs_[cur][0];
    short8 af[4], bf[4];
#pragma unroll
    for (int m = 0; m < 4; ++m)
      af[m] = *reinterpret_cast<const short8*>(ap + (wm * 64 + m * 16 + ro) * 32 + ko);
#pragma unroll
    for (int n = 0; n < 4; ++n)
      bf[n] = *reinterpret_cast<const short8*>(bpp + (wn * 64 + n * 16 + ro) * 32 + ko);
#pragma unroll
    for (int m = 0; m < 4; ++m)
#pragma unroll
      for (int n = 0; n < 4; ++n)
        acc[m][n] = __builtin_amdgcn_mfma_f32_16x16x32_bf16(af[m], bf[n], acc[m][n], 0, 0, 0);
    cur ^= 1;
  }
#pragma unroll
  for (int m = 0; m < 4; ++m) {
    int rr = r0 + wm * 64 + m * 16 + (lane >> 4) * 4;
#pragma unroll
    for (int n = 0; n < 4; ++n) {
      int cc = c0 + wn * 64 + n * 16 + (lane & 15);
#pragma unroll
      for (int v = 0; v < 4; ++v)
        C[(rr + v) * OO + cc] = acc[m][n][v];
    }
  }
}

extern "C" void kernel_launch(void* const* d_in, const int* in_sizes, int n_in,
                              void* d_out, int out_size, void* d_ws, size_t ws_size,
                              hipStream_t stream) {
  const float* x    = (const float*)d_in[0];
  const float* W    = (const float*)d_in[1];
  const float* Wp   = (const float*)d_in[2];
  const float* bp   = (const float*)d_in[3];
  const float* sim  = (const float*)d_in[4];
  const float* temp = (const float*)d_in[5];
  const float* Wd0  = (const float*)d_in[6];
  const float* Wu0  = (const float*)d_in[7];
  const float* Wd1  = (const float*)d_in[8];
  const float* Wu1  = (const float*)d_in[9];
  const float* Wd2  = (const float*)d_in[10];
  const float* Wu2  = (const float*)d_in[11];
  const float* Wd3  = (const float*)d_in[12];
  const float* Wu3  = (const float*)d_in[13];
  float* out = (float*)d_out;
  char* ws = (char*)d_ws;
  // ws layout (total 37,982,208 B):
  unsigned short* Ax  = (unsigned short*)ws;                 // [16384][1056] bf16 = 34,603,008
  unsigned short* Bx  = (unsigned short*)(ws + 34603008);    // [1024][1056] bf16 =  2,162,688
  float* WtL          = (float*)(ws + 36765696);             // [32][9472] f32    =  1,212,416
  float* simn         = (float*)(ws + 37978112);             // [256][4] f32      =      4,096

  prep2<<<1024, 256, 0, stream>>>(W, Wp, sim, Wd0, Wd1, Wd2, Wd3,
                                  Wu0, Wu1, Wu2, Wu3, WtL, Bx, Ax, simn);
  gate_gemm6<<<256, 512, 0, stream>>>(x, WtL, bp, simn, temp, Ax);
  main_gemm<<<dim3(8, 128), 256, 0, stream>>>(Ax, Bx, out);
}

// Round 7
// 138.191 us; speedup vs baseline: 1.7119x; 1.5576x over previous
//
#include <hip/hip_runtime.h>

#define TOK 16384
#define DD 1024
#define OO 1024
#define KE 1056     // 1024 + 16 lora cols + 16 pad
#define NB1 288     // B1 rows: 256 proj + 15 down + 17 zero pad
#define CLAMPV 4.605170185988091f

typedef __attribute__((ext_vector_type(8))) short short8;
typedef __attribute__((ext_vector_type(4))) float f32x4;

__device__ __forceinline__ unsigned short f2bf(float f) {
  unsigned int u = __float_as_uint(f);
  return (unsigned short)((u + 0x7FFFu + ((u >> 16) & 1u)) >> 16);
}

__device__ __forceinline__ void gload16(const unsigned short* g, unsigned short* l) {
  __builtin_amdgcn_global_load_lds(
      (const __attribute__((address_space(1))) void*)g,
      (__attribute__((address_space(3))) void*)l, 16, 0, 0);
}

__device__ __forceinline__ float down_val(int j, int d,
    const float* __restrict__ Wd0, const float* __restrict__ Wd1,
    const float* __restrict__ Wd2, const float* __restrict__ Wd3) {
  if (j == 0) return Wd0[d];
  if (j < 3) return Wd1[(j - 1) * DD + d];
  if (j < 7) return Wd2[(j - 3) * DD + d];
  if (j < 15) return Wd3[(j - 7) * DD + d];
  return 0.f;
}

// ---------------- kernel 0: prep (Bx bf16, B1 bf16, Ax pad, v4 = simn^T Wp, c4 = simn^T bp) ----------------
__global__ __launch_bounds__(256) void prep3(
    const float* __restrict__ W, const float* __restrict__ Wp,
    const float* __restrict__ sim, const float* __restrict__ bp,
    const float* __restrict__ Wd0, const float* __restrict__ Wd1,
    const float* __restrict__ Wd2, const float* __restrict__ Wd3,
    const float* __restrict__ Wu0, const float* __restrict__ Wu1,
    const float* __restrict__ Wu2, const float* __restrict__ Wu3,
    unsigned short* __restrict__ Bx, unsigned short* __restrict__ B1,
    unsigned short* __restrict__ Ax, float* __restrict__ v4,
    float* __restrict__ c4) {
  __shared__ float simn_l[256][4];
  __shared__ float part[4][4];
  const int tid = threadIdx.x;
  if (blockIdx.x < 4) {
    // --- simn (normalized sim columns) into LDS ---
    float4 sv = *(const float4*)&sim[tid * 4];
    float v[4] = {sv.x * sv.x, sv.y * sv.y, sv.z * sv.z, sv.w * sv.w};
#pragma unroll
    for (int off = 1; off < 64; off <<= 1) {
#pragma unroll
      for (int e = 0; e < 4; ++e) v[e] += __shfl_xor(v[e], off, 64);
    }
    int wv = tid >> 6, ln = tid & 63;
    if (ln == 0) { part[wv][0] = v[0]; part[wv][1] = v[1]; part[wv][2] = v[2]; part[wv][3] = v[3]; }
    __syncthreads();
    float n0 = fmaxf(sqrtf(part[0][0] + part[1][0] + part[2][0] + part[3][0]), 1e-12f);
    float n1 = fmaxf(sqrtf(part[0][1] + part[1][1] + part[2][1] + part[3][1]), 1e-12f);
    float n2 = fmaxf(sqrtf(part[0][2] + part[1][2] + part[2][2] + part[3][2]), 1e-12f);
    float n3 = fmaxf(sqrtf(part[0][3] + part[1][3] + part[2][3] + part[3][3]), 1e-12f);
    simn_l[tid][0] = sv.x / n0; simn_l[tid][1] = sv.y / n1;
    simn_l[tid][2] = sv.z / n2; simn_l[tid][3] = sv.w / n3;
    __syncthreads();
    // --- v4[e][d] = sum_j Wp[j][d] * simn[j][e], d = blk*256 + tid ---
    int d = blockIdx.x * 256 + tid;
    float a0 = 0.f, a1 = 0.f, a2 = 0.f, a3 = 0.f;
    for (int j = 0; j < 256; ++j) {
      float w = Wp[j * DD + d];
      a0 = __builtin_fmaf(w, simn_l[j][0], a0);
      a1 = __builtin_fmaf(w, simn_l[j][1], a1);
      a2 = __builtin_fmaf(w, simn_l[j][2], a2);
      a3 = __builtin_fmaf(w, simn_l[j][3], a3);
    }
    v4[d] = a0; v4[1024 + d] = a1; v4[2048 + d] = a2; v4[3072 + d] = a3;
    // --- c4[e] = sum_j simn[j][e] * bp[j] (block 0 only) ---
    if (blockIdx.x == 0) {
      float bpv = bp[tid];
      float pc[4] = {simn_l[tid][0] * bpv, simn_l[tid][1] * bpv,
                     simn_l[tid][2] * bpv, simn_l[tid][3] * bpv};
#pragma unroll
      for (int off = 1; off < 64; off <<= 1) {
#pragma unroll
        for (int e = 0; e < 4; ++e) pc[e] += __shfl_xor(pc[e], off, 64);
      }
      __syncthreads();
      if (ln == 0) { part[wv][0] = pc[0]; part[wv][1] = pc[1]; part[wv][2] = pc[2]; part[wv][3] = pc[3]; }
      __syncthreads();
      if (tid == 0) {
#pragma unroll
        for (int e = 0; e < 4; ++e)
          c4[e] = part[0][e] + part[1][e] + part[2][e] + part[3][e];
      }
    }
  }
  // --- bulk fill: B1, Bx, Ax pad cols ---
  const int nB1 = NB1 * DD;         // 294912
  const int nWb = OO * KE;          // 1081344
  const int nXpad = TOK * 16;       // 262144
  const int total = nB1 + nWb + nXpad;
  for (int i = blockIdx.x * 256 + tid; i < total; i += gridDim.x * 256) {
    if (i < nB1) {
      int r = i >> 10, c = i & 1023;
      float v = 0.f;
      if (r < 256) v = Wp[r * DD + c];
      else if (r < 271) v = down_val(r - 256, c, Wd0, Wd1, Wd2, Wd3);
      B1[i] = f2bf(v);
    } else if (i < nB1 + nWb) {
      int j = i - nB1;
      int o = j / KE, c = j - o * KE;
      float v = 0.f;
      if (c < 1024) v = W[o * DD + c];
      else if (c == 1024) v = Wu0[o];
      else if (c < 1027) v = Wu1[o * 2 + (c - 1025)];
      else if (c < 1031) v = Wu2[o * 4 + (c - 1027)];
      else if (c < 1039) v = Wu3[o * 8 + (c - 1031)];
      Bx[j] = f2bf(v);
    } else {
      int j = i - nB1 - nWb;
      int row = j >> 4, c = j & 15;
      Ax[row * KE + 1040 + c] = 0;
    }
  }
}

// ---------------- kernel 1: xconv — x -> Ax bf16 (cols 0..1023) + fp32 gate dots ----------------
// 1 wave per token; lane l handles cols {j*256 + l*4 : j=0..3}.
__global__ __launch_bounds__(256) void xconv(
    const float* __restrict__ x, const float* __restrict__ v4,
    float* __restrict__ dots, unsigned short* __restrict__ Ax) {
  const int wv = threadIdx.x >> 6, lane = threadIdx.x & 63;
  const int t = blockIdx.x * 4 + wv;
  const float* xr = &x[t * DD];
  unsigned short* ar = &Ax[t * KE];
  float a0 = 0.f, a1 = 0.f, a2 = 0.f, a3 = 0.f;
#pragma unroll
  for (int j = 0; j < 4; ++j) {
    int c = j * 256 + lane * 4;
    float4 xv = *(const float4*)&xr[c];
    float4 v0 = *(const float4*)&v4[c];
    float4 v1 = *(const float4*)&v4[1024 + c];
    float4 v2 = *(const float4*)&v4[2048 + c];
    float4 v3 = *(const float4*)&v4[3072 + c];
    a0 = __builtin_fmaf(xv.x, v0.x, __builtin_fmaf(xv.y, v0.y,
         __builtin_fmaf(xv.z, v0.z, __builtin_fmaf(xv.w, v0.w, a0))));
    a1 = __builtin_fmaf(xv.x, v1.x, __builtin_fmaf(xv.y, v1.y,
         __builtin_fmaf(xv.z, v1.z, __builtin_fmaf(xv.w, v1.w, a1))));
    a2 = __builtin_fmaf(xv.x, v2.x, __builtin_fmaf(xv.y, v2.y,
         __builtin_fmaf(xv.z, v2.z, __builtin_fmaf(xv.w, v2.w, a2))));
    a3 = __builtin_fmaf(xv.x, v3.x, __builtin_fmaf(xv.y, v3.y,
         __builtin_fmaf(xv.z, v3.z, __builtin_fmaf(xv.w, v3.w, a3))));
    union { unsigned short s[4]; uint2 q; } pk;
    pk.s[0] = f2bf(xv.x); pk.s[1] = f2bf(xv.y);
    pk.s[2] = f2bf(xv.z); pk.s[3] = f2bf(xv.w);
    *reinterpret_cast<uint2*>(&ar[c]) = pk.q;
  }
#pragma unroll
  for (int off = 1; off < 64; off <<= 1) {
    a0 += __shfl_xor(a0, off, 64);
    a1 += __shfl_xor(a1, off, 64);
    a2 += __shfl_xor(a2, off, 64);
    a3 += __shfl_xor(a3, off, 64);
  }
  if (lane == 0) {
    float4 o; o.x = a0; o.y = a1; o.z = a2; o.w = a3;
    *reinterpret_cast<float4*>(&dots[t * 4]) = o;
  }
}

// ---------------- kernel 2: gemm1f — bf16 MFMA proj/xdown GEMM + fused gate finalize ----------------
// Tile 64 rows x 288 cols, grid 256 (1 block/CU), 512 threads (8 waves: 4m x 2n).
// Epilogue: ssq over proj cols, logits from fp32 dots, softmax-top1, write Ax lora cols.
__global__ __launch_bounds__(512, 1) void gemm1f(
    unsigned short* __restrict__ Ax, const unsigned short* __restrict__ B1,
    const float* __restrict__ dots, const float* __restrict__ c4,
    const float* __restrict__ bp, const float* __restrict__ temp) {
  __shared__ __align__(16) unsigned short as1[2][64 * 32];
  __shared__ __align__(16) unsigned short bs1[2][NB1 * 32];
  __shared__ float ssq_s[2][64];
  __shared__ float xdown_s[64][16];
  const int tid = threadIdx.x;
  const int lane = tid & 63, wv = tid >> 6;
  const int wm = wv >> 1, wn = wv & 1;
  const int r0 = blockIdx.x * 64;
  const int ro = lane & 15, ko = (lane >> 4) * 8;
  const int srow = lane >> 2, scol = (lane & 3) * 8;   // staging: 16 rows x 32 cols per gload
  f32x4 acc[9] = {};

  // stage kt into buf: 22 chunks (0-3 = A rows 16c.., 4-21 = B1 rows 16b..)
#define STAGE1(KT, BUF)                                                          \
  for (int c = wv; c < 22; c += 8) {                                             \
    if (c < 4)                                                                   \
      gload16(&Ax[(r0 + c * 16 + srow) * KE + (KT) * 32 + scol],                 \
              &as1[BUF][c * 512]);                                               \
    else                                                                         \
      gload16(&B1[((c - 4) * 16 + srow) * DD + (KT) * 32 + scol],                \
              &bs1[BUF][(c - 4) * 512]);                                         \
  }

  STAGE1(0, 0)
  __syncthreads();
  int cur = 0;
  for (int kt = 0; kt < 32; ++kt) {
    if (kt < 31) { STAGE1(kt + 1, cur ^ 1) }
    const unsigned short* ap = &as1[cur][0];
    const unsigned short* bpp = &bs1[cur][0];
    short8 af = *reinterpret_cast<const short8*>(ap + (wm * 16 + ro) * 32 + ko);
#pragma unroll
    for (int n = 0; n < 9; ++n) {
      short8 bf = *reinterpret_cast<const short8*>(bpp + (wn * 144 + n * 16 + ro) * 32 + ko);
      acc[n] = __builtin_amdgcn_mfma_f32_16x16x32_bf16(af, bf, acc[n], 0, 0, 0);
    }
    if (kt < 31) {
      __syncthreads();
      cur ^= 1;
    }
  }

  // ---- epilogue: per-thread ssq over proj cols (col < 256), bias added ----
  float ssqp[4] = {};
#pragma unroll
  for (int n = 0; n < 9; ++n) {
    int col = wn * 144 + n * 16 + ro;
    if (col < 256) {
      float b = bp[col];
#pragma unroll
      for (int r = 0; r < 4; ++r) {
        float a = acc[n][r] + b;
        ssqp[r] = __builtin_fmaf(a, a, ssqp[r]);
      }
    }
  }
#pragma unroll
  for (int off = 1; off < 16; off <<= 1) {
#pragma unroll
    for (int r = 0; r < 4; ++r) ssqp[r] += __shfl_xor(ssqp[r], off, 64);
  }
  if (ro == 0) {
#pragma unroll
    for (int r = 0; r < 4; ++r)
      ssq_s[wn][wm * 16 + (lane >> 4) * 4 + r] = ssqp[r];
  }
  // xdown cols 256..270 live in wn=1, n=7, ro<15
  if (wn == 1 && ro < 15) {
#pragma unroll
    for (int r = 0; r < 4; ++r)
      xdown_s[wm * 16 + (lane >> 4) * 4 + r][ro] = acc[7][r];
  }
  __syncthreads();

  if (tid < 64) {
    const int row = tid, t = r0 + row;
    float ssqT = ssq_s[0][row] + ssq_s[1][row];
    float4 dt = *reinterpret_cast<const float4*>(&dots[t * 4]);
    float4 cc = *reinterpret_cast<const float4*>(c4);
    float scale = expf(fminf(temp[0], CLAMPV));
    float inv = scale / fmaxf(sqrtf(ssqT), 1e-12f);
    float l[4];
    l[0] = (dt.x + cc.x) * inv; l[1] = (dt.y + cc.y) * inv;
    l[2] = (dt.z + cc.z) * inv; l[3] = (dt.w + cc.w) * inv;
    int be = 0; float m = l[0];
    if (l[1] > m) { m = l[1]; be = 1; }
    if (l[2] > m) { m = l[2]; be = 2; }
    if (l[3] > m) { m = l[3]; be = 3; }
    float den = expf(l[0] - m) + expf(l[1] - m) + expf(l[2] - m) + expf(l[3] - m);
    float g = 1.0f / den;
    int off = (1 << be) - 1;   // {0,1,3,7}
    int rr = 1 << be;          // {1,2,4,8}
    union { unsigned short s[16]; uint4 v[2]; } o;
#pragma unroll
    for (int j = 0; j < 16; ++j) {
      float dv = xdown_s[row][j & 15];
      float v = (j >= off && j < off + rr) ? g * dv : 0.f;
      o.s[j] = f2bf(v);
    }
    uint4* dst = reinterpret_cast<uint4*>(&Ax[t * KE + 1024]);
    dst[0] = o.v[0];
    dst[1] = o.v[1];
  }
}

// ---------------- kernel 3: bf16 MFMA GEMM C[16384,1024] = A[16384,1056] @ B[1024,1056]^T ----------------
__global__ __launch_bounds__(256) void main_gemm(
    const unsigned short* __restrict__ A, const unsigned short* __restrict__ Bm,
    float* __restrict__ C) {
  __shared__ __align__(16) unsigned short as_[2][128 * 32];
  __shared__ __align__(16) unsigned short bs_[2][128 * 32];
  const int tid = threadIdx.x;
  const int lane = tid & 63, wv = tid >> 6;
  const int wm = wv >> 1, wn = wv & 1;
  const int r0 = blockIdx.y * 128, c0 = blockIdx.x * 128;
  f32x4 acc[4][4] = {};
  const int se = wv * 512 + lane * 8;
  const int sr = se >> 5, sc = se & 31;
  const unsigned short* ga0 = &A[(r0 + sr) * KE + sc];
  const unsigned short* gb0 = &Bm[(c0 + sr) * KE + sc];
  gload16(ga0, &as_[0][wv * 512]);
  gload16(ga0 + 64 * KE, &as_[0][2048 + wv * 512]);
  gload16(gb0, &bs_[0][wv * 512]);
  gload16(gb0 + 64 * KE, &bs_[0][2048 + wv * 512]);
  const int ro = lane & 15, ko = (lane >> 4) * 8;
  int cur = 0;
  for (int kt = 0; kt < 33; ++kt) {
    __syncthreads();
    if (kt + 1 < 33) {
      const unsigned short* ga = ga0 + (kt + 1) * 32;
      const unsigned short* gb = gb0 + (kt + 1) * 32;
      int nb = cur ^ 1;
      gload16(ga, &as_[nb][wv * 512]);
      gload16(ga + 64 * KE, &as_[nb][2048 + wv * 512]);
      gload16(gb, &bs_[nb][wv * 512]);
      gload16(gb + 64 * KE, &bs_[nb][2048 + wv * 512]);
    }
    const unsigned short* ap = &as_[cur][0];
    const unsigned short* bpp = &bs_[cur][0];
    short8 af[4], bf[4];
#pragma unroll
    for (int m = 0; m < 4; ++m)
      af[m] = *reinterpret_cast<const short8*>(ap + (wm * 64 + m * 16 + ro) * 32 + ko);
#pragma unroll
    for (int n = 0; n < 4; ++n)
      bf[n] = *reinterpret_cast<const short8*>(bpp + (wn * 64 + n * 16 + ro) * 32 + ko);
#pragma unroll
    for (int m = 0; m < 4; ++m)
#pragma unroll
      for (int n = 0; n < 4; ++n)
        acc[m][n] = __builtin_amdgcn_mfma_f32_16x16x32_bf16(af[m], bf[n], acc[m][n], 0, 0, 0);
    cur ^= 1;
  }
#pragma unroll
  for (int m = 0; m < 4; ++m) {
    int rr = r0 + wm * 64 + m * 16 + (lane >> 4) * 4;
#pragma unroll
    for (int n = 0; n < 4; ++n) {
      int cc = c0 + wn * 64 + n * 16 + (lane & 15);
#pragma unroll
      for (int v = 0; v < 4; ++v)
        C[(rr + v) * OO + cc] = acc[m][n][v];
    }
  }
}

extern "C" void kernel_launch(void* const* d_in, const int* in_sizes, int n_in,
                              void* d_out, int out_size, void* d_ws, size_t ws_size,
                              hipStream_t stream) {
  const float* x    = (const float*)d_in[0];
  const float* W    = (const float*)d_in[1];
  const float* Wp   = (const float*)d_in[2];
  const float* bp   = (const float*)d_in[3];
  const float* sim  = (const float*)d_in[4];
  const float* temp = (const float*)d_in[5];
  const float* Wd0  = (const float*)d_in[6];
  const float* Wu0  = (const float*)d_in[7];
  const float* Wd1  = (const float*)d_in[8];
  const float* Wu1  = (const float*)d_in[9];
  const float* Wd2  = (const float*)d_in[10];
  const float* Wu2  = (const float*)d_in[11];
  const float* Wd3  = (const float*)d_in[12];
  const float* Wu3  = (const float*)d_in[13];
  float* out = (float*)d_out;
  char* ws = (char*)d_ws;
  // ws layout (total 37,634,112 B):
  unsigned short* Ax  = (unsigned short*)ws;                 // [16384][1056] bf16 = 34,603,008
  unsigned short* Bx  = (unsigned short*)(ws + 34603008);    // [1024][1056] bf16 =  2,162,688
  unsigned short* B1  = (unsigned short*)(ws + 36765696);    // [288][1024] bf16  =    589,824
  float* v4           = (float*)(ws + 37355520);             // [4][1024] f32     =     16,384
  float* dots         = (float*)(ws + 37371904);             // [16384][4] f32    =    262,144
  float* c4           = (float*)(ws + 37634048);             // [4] f32           =         64

  prep3<<<1024, 256, 0, stream>>>(W, Wp, sim, bp, Wd0, Wd1, Wd2, Wd3,
                                  Wu0, Wu1, Wu2, Wu3, Bx, B1, Ax, v4, c4);
  xconv<<<4096, 256, 0, stream>>>(x, v4, dots, Ax);
  gemm1f<<<256, 512, 0, stream>>>(Ax, B1, dots, c4, bp, temp);
  main_gemm<<<dim3(8, 128), 256, 0, stream>>>(Ax, Bx, out);
}

// Round 8
// 131.741 us; speedup vs baseline: 1.7957x; 1.0490x over previous
//
#include <hip/hip_runtime.h>

#define TOK 16384
#define DD 1024
#define OO 1024
#define KE 1056     // 1024 + 16 lora cols + 16 pad
#define NB1 288     // B1 rows: 256 proj + 15 down + 17 zero pad
#define CLAMPV 4.605170185988091f

typedef __attribute__((ext_vector_type(8))) short short8;
typedef __attribute__((ext_vector_type(4))) float f32x4;

__device__ __forceinline__ unsigned short f2bf(float f) {
  unsigned int u = __float_as_uint(f);
  return (unsigned short)((u + 0x7FFFu + ((u >> 16) & 1u)) >> 16);
}

__device__ __forceinline__ void gload16(const unsigned short* g, unsigned short* l) {
  __builtin_amdgcn_global_load_lds(
      (const __attribute__((address_space(1))) void*)g,
      (__attribute__((address_space(3))) void*)l, 16, 0, 0);
}

__device__ __forceinline__ float down_val(int j, int d,
    const float* __restrict__ Wd0, const float* __restrict__ Wd1,
    const float* __restrict__ Wd2, const float* __restrict__ Wd3) {
  if (j == 0) return Wd0[d];
  if (j < 3) return Wd1[(j - 1) * DD + d];
  if (j < 7) return Wd2[(j - 3) * DD + d];
  if (j < 15) return Wd3[(j - 7) * DD + d];
  return 0.f;
}

// ---------------- kernel 0: prep (Bx bf16, B1 bf16, Ax pad, v4 = simn^T Wp, c4 = simn^T bp) ----------------
__global__ __launch_bounds__(256) void prep3(
    const float* __restrict__ W, const float* __restrict__ Wp,
    const float* __restrict__ sim, const float* __restrict__ bp,
    const float* __restrict__ Wd0, const float* __restrict__ Wd1,
    const float* __restrict__ Wd2, const float* __restrict__ Wd3,
    const float* __restrict__ Wu0, const float* __restrict__ Wu1,
    const float* __restrict__ Wu2, const float* __restrict__ Wu3,
    unsigned short* __restrict__ Bx, unsigned short* __restrict__ B1,
    unsigned short* __restrict__ Ax, float* __restrict__ v4,
    float* __restrict__ c4) {
  __shared__ float simn_l[256][4];
  __shared__ float part[4][4];
  const int tid = threadIdx.x;
  if (blockIdx.x < 4) {
    // --- simn (normalized sim columns) into LDS ---
    float4 sv = *(const float4*)&sim[tid * 4];
    float v[4] = {sv.x * sv.x, sv.y * sv.y, sv.z * sv.z, sv.w * sv.w};
#pragma unroll
    for (int off = 1; off < 64; off <<= 1) {
#pragma unroll
      for (int e = 0; e < 4; ++e) v[e] += __shfl_xor(v[e], off, 64);
    }
    int wv = tid >> 6, ln = tid & 63;
    if (ln == 0) { part[wv][0] = v[0]; part[wv][1] = v[1]; part[wv][2] = v[2]; part[wv][3] = v[3]; }
    __syncthreads();
    float n0 = fmaxf(sqrtf(part[0][0] + part[1][0] + part[2][0] + part[3][0]), 1e-12f);
    float n1 = fmaxf(sqrtf(part[0][1] + part[1][1] + part[2][1] + part[3][1]), 1e-12f);
    float n2 = fmaxf(sqrtf(part[0][2] + part[1][2] + part[2][2] + part[3][2]), 1e-12f);
    float n3 = fmaxf(sqrtf(part[0][3] + part[1][3] + part[2][3] + part[3][3]), 1e-12f);
    simn_l[tid][0] = sv.x / n0; simn_l[tid][1] = sv.y / n1;
    simn_l[tid][2] = sv.z / n2; simn_l[tid][3] = sv.w / n3;
    __syncthreads();
    // --- v4[e][d] = sum_j Wp[j][d] * simn[j][e], d = blk*256 + tid ---
    int d = blockIdx.x * 256 + tid;
    float a0 = 0.f, a1 = 0.f, a2 = 0.f, a3 = 0.f;
    for (int j = 0; j < 256; ++j) {
      float w = Wp[j * DD + d];
      a0 = __builtin_fmaf(w, simn_l[j][0], a0);
      a1 = __builtin_fmaf(w, simn_l[j][1], a1);
      a2 = __builtin_fmaf(w, simn_l[j][2], a2);
      a3 = __builtin_fmaf(w, simn_l[j][3], a3);
    }
    v4[d] = a0; v4[1024 + d] = a1; v4[2048 + d] = a2; v4[3072 + d] = a3;
    // --- c4[e] = sum_j simn[j][e] * bp[j] (block 0 only) ---
    if (blockIdx.x == 0) {
      float bpv = bp[tid];
      float pc[4] = {simn_l[tid][0] * bpv, simn_l[tid][1] * bpv,
                     simn_l[tid][2] * bpv, simn_l[tid][3] * bpv};
#pragma unroll
      for (int off = 1; off < 64; off <<= 1) {
#pragma unroll
        for (int e = 0; e < 4; ++e) pc[e] += __shfl_xor(pc[e], off, 64);
      }
      __syncthreads();
      if (ln == 0) { part[wv][0] = pc[0]; part[wv][1] = pc[1]; part[wv][2] = pc[2]; part[wv][3] = pc[3]; }
      __syncthreads();
      if (tid == 0) {
#pragma unroll
        for (int e = 0; e < 4; ++e)
          c4[e] = part[0][e] + part[1][e] + part[2][e] + part[3][e];
      }
    }
  }
  // --- bulk fill: B1, Bx, Ax pad cols ---
  const int nB1 = NB1 * DD;         // 294912
  const int nWb = OO * KE;          // 1081344
  const int nXpad = TOK * 16;       // 262144
  const int total = nB1 + nWb + nXpad;
  for (int i = blockIdx.x * 256 + tid; i < total; i += gridDim.x * 256) {
    if (i < nB1) {
      int r = i >> 10, c = i & 1023;
      float v = 0.f;
      if (r < 256) v = Wp[r * DD + c];
      else if (r < 271) v = down_val(r - 256, c, Wd0, Wd1, Wd2, Wd3);
      B1[i] = f2bf(v);
    } else if (i < nB1 + nWb) {
      int j = i - nB1;
      int o = j / KE, c = j - o * KE;
      float v = 0.f;
      if (c < 1024) v = W[o * DD + c];
      else if (c == 1024) v = Wu0[o];
      else if (c < 1027) v = Wu1[o * 2 + (c - 1025)];
      else if (c < 1031) v = Wu2[o * 4 + (c - 1027)];
      else if (c < 1039) v = Wu3[o * 8 + (c - 1031)];
      Bx[j] = f2bf(v);
    } else {
      int j = i - nB1 - nWb;
      int row = j >> 4, c = j & 15;
      Ax[row * KE + 1040 + c] = 0;
    }
  }
}

// ---------------- kernel 1: gemm2f — fused x->bf16 conversion + fp32 gate dots +
//                  bf16 MFMA proj/xdown GEMM + gate finalize ----------------
// Tile 64 rows x 288 cols, grid 256 (1 block/CU), 512 threads (8 waves: 4m x 2n).
// A-tile reg-staged from x (fp32->bf16 in regs, ds_write + Ax global write);
// B1 staged via global_load_lds. Epilogue: ssq, logits from fp32 dots,
// softmax-top1, write Ax lora cols.
__global__ __launch_bounds__(512, 1) void gemm2f(
    const float* __restrict__ x, const float* __restrict__ v4,
    unsigned short* __restrict__ Ax, const unsigned short* __restrict__ B1,
    const float* __restrict__ c4, const float* __restrict__ bp,
    const float* __restrict__ temp) {
  __shared__ __align__(16) unsigned short as1[2][64 * 32];
  __shared__ __align__(16) unsigned short bs1[2][NB1 * 32];
  __shared__ float ssq_s[2][64];
  __shared__ float xdown_s[64][16];
  __shared__ __align__(16) float dots_s[64][4];
  const int tid = threadIdx.x;
  const int lane = tid & 63, wv = tid >> 6;
  const int wm = wv >> 1, wn = wv & 1;
  const int r0 = blockIdx.x * 64;
  const int ro = lane & 15, ko = (lane >> 4) * 8;
  const int srow = lane >> 2, scol = (lane & 3) * 8;   // B1 staging: 16 rows x 32 cols / gload
  const int xr = tid >> 3;          // x staging: row 0..63
  const int xc = (tid & 7) * 4;     // x staging: col quad within 32-k chunk
  const float* xgp = &x[(r0 + xr) * DD + xc];
  unsigned short* axp = &Ax[(r0 + xr) * KE + xc];
  f32x4 acc[9] = {};
  float dotp[4] = {};

#define STB1(KT, BUF)                                                         \
  for (int c = wv; c < 18; c += 8)                                            \
    gload16(&B1[(c * 16 + srow) * DD + (KT) * 32 + scol], &bs1[BUF][c * 512]);

#define XSTG(KT, BUF) do {                                                    \
    float4 xv = *(const float4*)(xgp + (KT) * 32);                            \
    float4 va = *(const float4*)&v4[(KT) * 32 + xc];                          \
    float4 vb = *(const float4*)&v4[1024 + (KT) * 32 + xc];                   \
    float4 vc = *(const float4*)&v4[2048 + (KT) * 32 + xc];                   \
    float4 vd = *(const float4*)&v4[3072 + (KT) * 32 + xc];                   \
    dotp[0] = __builtin_fmaf(xv.x, va.x, __builtin_fmaf(xv.y, va.y,           \
              __builtin_fmaf(xv.z, va.z, __builtin_fmaf(xv.w, va.w, dotp[0])))); \
    dotp[1] = __builtin_fmaf(xv.x, vb.x, __builtin_fmaf(xv.y, vb.y,           \
              __builtin_fmaf(xv.z, vb.z, __builtin_fmaf(xv.w, vb.w, dotp[1])))); \
    dotp[2] = __builtin_fmaf(xv.x, vc.x, __builtin_fmaf(xv.y, vc.y,           \
              __builtin_fmaf(xv.z, vc.z, __builtin_fmaf(xv.w, vc.w, dotp[2])))); \
    dotp[3] = __builtin_fmaf(xv.x, vd.x, __builtin_fmaf(xv.y, vd.y,           \
              __builtin_fmaf(xv.z, vd.z, __builtin_fmaf(xv.w, vd.w, dotp[3])))); \
    union { unsigned short s[4]; uint2 q; } pk;                               \
    pk.s[0] = f2bf(xv.x); pk.s[1] = f2bf(xv.y);                               \
    pk.s[2] = f2bf(xv.z); pk.s[3] = f2bf(xv.w);                               \
    *reinterpret_cast<uint2*>(axp + (KT) * 32) = pk.q;                        \
    *reinterpret_cast<uint2*>(&as1[BUF][xr * 32 + xc]) = pk.q;                \
  } while (0)

  XSTG(0, 0);
  STB1(0, 0)
  __syncthreads();
  int cur = 0;
  for (int kt = 0; kt < 32; ++kt) {
    if (kt < 31) {
      XSTG(kt + 1, cur ^ 1);
      STB1(kt + 1, cur ^ 1)
    }
    const unsigned short* ap = &as1[cur][0];
    const unsigned short* bpp = &bs1[cur][0];
    short8 af = *reinterpret_cast<const short8*>(ap + (wm * 16 + ro) * 32 + ko);
#pragma unroll
    for (int n = 0; n < 9; ++n) {
      short8 bf = *reinterpret_cast<const short8*>(bpp + (wn * 144 + n * 16 + ro) * 32 + ko);
      acc[n] = __builtin_amdgcn_mfma_f32_16x16x32_bf16(af, bf, acc[n], 0, 0, 0);
    }
    if (kt < 31) {
      __syncthreads();
      cur ^= 1;
    }
  }

  // ---- fp32 dots: reduce over the 8 lanes sharing a row (lane bits 0..2) ----
#pragma unroll
  for (int off = 1; off < 8; off <<= 1) {
#pragma unroll
    for (int e = 0; e < 4; ++e) dotp[e] += __shfl_xor(dotp[e], off, 64);
  }
  if ((lane & 7) == 0) {
    dots_s[xr][0] = dotp[0]; dots_s[xr][1] = dotp[1];
    dots_s[xr][2] = dotp[2]; dots_s[xr][3] = dotp[3];
  }

  // ---- epilogue: per-thread ssq over proj cols (col < 256), bias added ----
  float ssqp[4] = {};
#pragma unroll
  for (int n = 0; n < 9; ++n) {
    int col = wn * 144 + n * 16 + ro;
    if (col < 256) {
      float b = bp[col];
#pragma unroll
      for (int r = 0; r < 4; ++r) {
        float a = acc[n][r] + b;
        ssqp[r] = __builtin_fmaf(a, a, ssqp[r]);
      }
    }
  }
#pragma unroll
  for (int off = 1; off < 16; off <<= 1) {
#pragma unroll
    for (int r = 0; r < 4; ++r) ssqp[r] += __shfl_xor(ssqp[r], off, 64);
  }
  if (ro == 0) {
#pragma unroll
    for (int r = 0; r < 4; ++r)
      ssq_s[wn][wm * 16 + (lane >> 4) * 4 + r] = ssqp[r];
  }
  // xdown cols 256..270 live in wn=1, n=7, ro<15
  if (wn == 1 && ro < 15) {
#pragma unroll
    for (int r = 0; r < 4; ++r)
      xdown_s[wm * 16 + (lane >> 4) * 4 + r][ro] = acc[7][r];
  }
  __syncthreads();

  if (tid < 64) {
    const int row = tid, t = r0 + row;
    float ssqT = ssq_s[0][row] + ssq_s[1][row];
    float4 cc = *reinterpret_cast<const float4*>(c4);
    float scale = expf(fminf(temp[0], CLAMPV));
    float inv = scale / fmaxf(sqrtf(ssqT), 1e-12f);
    float l[4];
    l[0] = (dots_s[row][0] + cc.x) * inv; l[1] = (dots_s[row][1] + cc.y) * inv;
    l[2] = (dots_s[row][2] + cc.z) * inv; l[3] = (dots_s[row][3] + cc.w) * inv;
    int be = 0; float m = l[0];
    if (l[1] > m) { m = l[1]; be = 1; }
    if (l[2] > m) { m = l[2]; be = 2; }
    if (l[3] > m) { m = l[3]; be = 3; }
    float den = expf(l[0] - m) + expf(l[1] - m) + expf(l[2] - m) + expf(l[3] - m);
    float g = 1.0f / den;
    int off = (1 << be) - 1;   // {0,1,3,7}
    int rr = 1 << be;          // {1,2,4,8}
    union { unsigned short s[16]; uint4 v[2]; } o;
#pragma unroll
    for (int j = 0; j < 16; ++j) {
      float dv = xdown_s[row][j & 15];
      float v = (j >= off && j < off + rr) ? g * dv : 0.f;
      o.s[j] = f2bf(v);
    }
    uint4* dst = reinterpret_cast<uint4*>(&Ax[t * KE + 1024]);
    dst[0] = o.v[0];
    dst[1] = o.v[1];
  }
}

// ---------------- kernel 2: bf16 MFMA GEMM C[16384,1024] = A[16384,1056] @ B[1024,1056]^T ----------------
// XCD-chunked blockIdx swizzle: XCD k owns 16 contiguous row-panels x all 8 col-blocks,
// so each A-panel is HBM-fetched once and L2-served to the other 7 blocks.
__global__ __launch_bounds__(256) void main_gemm(
    const unsigned short* __restrict__ A, const unsigned short* __restrict__ Bm,
    float* __restrict__ C) {
  __shared__ __align__(16) unsigned short as_[2][128 * 32];
  __shared__ __align__(16) unsigned short bs_[2][128 * 32];
  const int tid = threadIdx.x;
  const int lane = tid & 63, wv = tid >> 6;
  const int wm = wv >> 1, wn = wv & 1;
  const int d = blockIdx.y * 8 + blockIdx.x;      // hardware dispatch order (x fastest)
  const int t = (d & 7) * 128 + (d >> 3);         // bijective (1024 = 8*128)
  const int bx = t & 7, by = t >> 3;
  const int r0 = by * 128, c0 = bx * 128;
  f32x4 acc[4][4] = {};
  const int se = wv * 512 + lane * 8;
  const int sr = se >> 5, sc = se & 31;
  const unsigned short* ga0 = &A[(r0 + sr) * KE + sc];
  const unsigned short* gb0 = &Bm[(c0 + sr) * KE + sc];
  gload16(ga0, &as_[0][wv * 512]);
  gload16(ga0 + 64 * KE, &as_[0][2048 + wv * 512]);
  gload16(gb0, &bs_[0][wv * 512]);
  gload16(gb0 + 64 * KE, &bs_[0][2048 + wv * 512]);
  const int ro = lane & 15, ko = (lane >> 4) * 8;
  int cur = 0;
  for (int kt = 0; kt < 33; ++kt) {
    __syncthreads();
    if (kt + 1 < 33) {
      const unsigned short* ga = ga0 + (kt + 1) * 32;
      const unsigned short* gb = gb0 + (kt + 1) * 32;
      int nb = cur ^ 1;
      gload16(ga, &as_[nb][wv * 512]);
      gload16(ga + 64 * KE, &as_[nb][2048 + wv * 512]);
      gload16(gb, &bs_[nb][wv * 512]);
      gload16(gb + 64 * KE, &bs_[nb][2048 + wv * 512]);
    }
    const unsigned short* ap = &as_[cur][0];
    const unsigned short* bpp = &bs_[cur][0];
    short8 af[4], bf[4];
#pragma unroll
    for (int m = 0; m < 4; ++m)
      af[m] = *reinterpret_cast<const short8*>(ap + (wm * 64 + m * 16 + ro) * 32 + ko);
#pragma unroll
    for (int n = 0; n < 4; ++n)
      bf[n] = *reinterpret_cast<const short8*>(bpp + (wn * 64 + n * 16 + ro) * 32 + ko);
#pragma unroll
    for (int m = 0; m < 4; ++m)
#pragma unroll
      for (int n = 0; n < 4; ++n)
        acc[m][n] = __builtin_amdgcn_mfma_f32_16x16x32_bf16(af[m], bf[n], acc[m][n], 0, 0, 0);
    cur ^= 1;
  }
#pragma unroll
  for (int m = 0; m < 4; ++m) {
    int rr = r0 + wm * 64 + m * 16 + (lane >> 4) * 4;
#pragma unroll
    for (int n = 0; n < 4; ++n) {
      int cc = c0 + wn * 64 + n * 16 + (lane & 15);
#pragma unroll
      for (int v = 0; v < 4; ++v)
        C[(rr + v) * OO + cc] = acc[m][n][v];
    }
  }
}

extern "C" void kernel_launch(void* const* d_in, const int* in_sizes, int n_in,
                              void* d_out, int out_size, void* d_ws, size_t ws_size,
                              hipStream_t stream) {
  const float* x    = (const float*)d_in[0];
  const float* W    = (const float*)d_in[1];
  const float* Wp   = (const float*)d_in[2];
  const float* bp   = (const float*)d_in[3];
  const float* sim  = (const float*)d_in[4];
  const float* temp = (const float*)d_in[5];
  const float* Wd0  = (const float*)d_in[6];
  const float* Wu0  = (const float*)d_in[7];
  const float* Wd1  = (const float*)d_in[8];
  const float* Wu1  = (const float*)d_in[9];
  const float* Wd2  = (const float*)d_in[10];
  const float* Wu2  = (const float*)d_in[11];
  const float* Wd3  = (const float*)d_in[12];
  const float* Wu3  = (const float*)d_in[13];
  float* out = (float*)d_out;
  char* ws = (char*)d_ws;
  // ws layout (total 37,371,968 B):
  unsigned short* Ax  = (unsigned short*)ws;                 // [16384][1056] bf16 = 34,603,008
  unsigned short* Bx  = (unsigned short*)(ws + 34603008);    // [1024][1056] bf16 =  2,162,688
  unsigned short* B1  = (unsigned short*)(ws + 36765696);    // [288][1024] bf16  =    589,824
  float* v4           = (float*)(ws + 37355520);             // [4][1024] f32     =     16,384
  float* c4           = (float*)(ws + 37371904);             // [4] f32           =         64

  prep3<<<1024, 256, 0, stream>>>(W, Wp, sim, bp, Wd0, Wd1, Wd2, Wd3,
                                  Wu0, Wu1, Wu2, Wu3, Bx, B1, Ax, v4, c4);
  gemm2f<<<256, 512, 0, stream>>>(x, v4, Ax, B1, c4, bp, temp);
  main_gemm<<<dim3(8, 128), 256, 0, stream>>>(Ax, Bx, out);
}

// Round 9
// 108.123 us; speedup vs baseline: 2.1879x; 1.2184x over previous
//
#include <hip/hip_runtime.h>

#define TOK 16384
#define DD 1024
#define OO 1024
#define KE 1152     // 1024 + 16 lora cols + 112 zero pad (18 K-tiles of 64)
#define NT 18       // K-tiles in main GEMM
#define NB1 288     // B1 rows: 256 proj + 15 down + 17 zero pad
#define CLAMPV 4.605170185988091f

typedef __attribute__((ext_vector_type(8))) short short8;
typedef __attribute__((ext_vector_type(4))) float f32x4;

__device__ __forceinline__ unsigned short f2bf(float f) {
  unsigned int u = __float_as_uint(f);
  return (unsigned short)((u + 0x7FFFu + ((u >> 16) & 1u)) >> 16);
}

__device__ __forceinline__ void gload16(const unsigned short* g, unsigned short* l) {
  __builtin_amdgcn_global_load_lds(
      (const __attribute__((address_space(1))) void*)g,
      (__attribute__((address_space(3))) void*)l, 16, 0, 0);
}

__device__ __forceinline__ float down_val(int j, int d,
    const float* __restrict__ Wd0, const float* __restrict__ Wd1,
    const float* __restrict__ Wd2, const float* __restrict__ Wd3) {
  if (j == 0) return Wd0[d];
  if (j < 3) return Wd1[(j - 1) * DD + d];
  if (j < 7) return Wd2[(j - 3) * DD + d];
  if (j < 15) return Wd3[(j - 7) * DD + d];
  return 0.f;
}

// ---------------- kernel 0: prep (Bx bf16, B1 bf16, Ax pad, v4 = simn^T Wp, c4 = simn^T bp) ----------------
__global__ __launch_bounds__(256) void prep3(
    const float* __restrict__ W, const float* __restrict__ Wp,
    const float* __restrict__ sim, const float* __restrict__ bp,
    const float* __restrict__ Wd0, const float* __restrict__ Wd1,
    const float* __restrict__ Wd2, const float* __restrict__ Wd3,
    const float* __restrict__ Wu0, const float* __restrict__ Wu1,
    const float* __restrict__ Wu2, const float* __restrict__ Wu3,
    unsigned short* __restrict__ Bx, unsigned short* __restrict__ B1,
    unsigned short* __restrict__ Ax, float* __restrict__ v4,
    float* __restrict__ c4) {
  __shared__ float simn_l[256][4];
  __shared__ float part[4][4];
  const int tid = threadIdx.x;
  if (blockIdx.x < 4) {
    float4 sv = *(const float4*)&sim[tid * 4];
    float v[4] = {sv.x * sv.x, sv.y * sv.y, sv.z * sv.z, sv.w * sv.w};
#pragma unroll
    for (int off = 1; off < 64; off <<= 1) {
#pragma unroll
      for (int e = 0; e < 4; ++e) v[e] += __shfl_xor(v[e], off, 64);
    }
    int wv = tid >> 6, ln = tid & 63;
    if (ln == 0) { part[wv][0] = v[0]; part[wv][1] = v[1]; part[wv][2] = v[2]; part[wv][3] = v[3]; }
    __syncthreads();
    float n0 = fmaxf(sqrtf(part[0][0] + part[1][0] + part[2][0] + part[3][0]), 1e-12f);
    float n1 = fmaxf(sqrtf(part[0][1] + part[1][1] + part[2][1] + part[3][1]), 1e-12f);
    float n2 = fmaxf(sqrtf(part[0][2] + part[1][2] + part[2][2] + part[3][2]), 1e-12f);
    float n3 = fmaxf(sqrtf(part[0][3] + part[1][3] + part[2][3] + part[3][3]), 1e-12f);
    simn_l[tid][0] = sv.x / n0; simn_l[tid][1] = sv.y / n1;
    simn_l[tid][2] = sv.z / n2; simn_l[tid][3] = sv.w / n3;
    __syncthreads();
    int d = blockIdx.x * 256 + tid;
    float a0 = 0.f, a1 = 0.f, a2 = 0.f, a3 = 0.f;
    for (int j = 0; j < 256; ++j) {
      float w = Wp[j * DD + d];
      a0 = __builtin_fmaf(w, simn_l[j][0], a0);
      a1 = __builtin_fmaf(w, simn_l[j][1], a1);
      a2 = __builtin_fmaf(w, simn_l[j][2], a2);
      a3 = __builtin_fmaf(w, simn_l[j][3], a3);
    }
    v4[d] = a0; v4[1024 + d] = a1; v4[2048 + d] = a2; v4[3072 + d] = a3;
    if (blockIdx.x == 0) {
      float bpv = bp[tid];
      float pc[4] = {simn_l[tid][0] * bpv, simn_l[tid][1] * bpv,
                     simn_l[tid][2] * bpv, simn_l[tid][3] * bpv};
#pragma unroll
      for (int off = 1; off < 64; off <<= 1) {
#pragma unroll
        for (int e = 0; e < 4; ++e) pc[e] += __shfl_xor(pc[e], off, 64);
      }
      __syncthreads();
      if (ln == 0) { part[wv][0] = pc[0]; part[wv][1] = pc[1]; part[wv][2] = pc[2]; part[wv][3] = pc[3]; }
      __syncthreads();
      if (tid == 0) {
#pragma unroll
        for (int e = 0; e < 4; ++e)
          c4[e] = part[0][e] + part[1][e] + part[2][e] + part[3][e];
      }
    }
  }
  const int nB1 = NB1 * DD;         // 294912
  const int nWb = OO * KE;          // 1179648
  const int nXpad = TOK * 112;      // 1835008 (cols 1040..1151)
  const int total = nB1 + nWb + nXpad;
  for (int i = blockIdx.x * 256 + tid; i < total; i += gridDim.x * 256) {
    if (i < nB1) {
      int r = i >> 10, c = i & 1023;
      float v = 0.f;
      if (r < 256) v = Wp[r * DD + c];
      else if (r < 271) v = down_val(r - 256, c, Wd0, Wd1, Wd2, Wd3);
      B1[i] = f2bf(v);
    } else if (i < nB1 + nWb) {
      int j = i - nB1;
      int o = j / KE, c = j - o * KE;
      float v = 0.f;
      if (c < 1024) v = W[o * DD + c];
      else if (c == 1024) v = Wu0[o];
      else if (c < 1027) v = Wu1[o * 2 + (c - 1025)];
      else if (c < 1031) v = Wu2[o * 4 + (c - 1027)];
      else if (c < 1039) v = Wu3[o * 8 + (c - 1031)];
      Bx[j] = f2bf(v);
    } else {
      int j = i - nB1 - nWb;
      int row = j / 112, c = j - row * 112;
      Ax[row * KE + 1040 + c] = 0;
    }
  }
}

// ---------------- kernel 1: gemm2f — fused x->bf16 + fp32 gate dots + bf16 MFMA
//                  proj/xdown GEMM + gate finalize (unchanged from r8, KE bump) ------------
__global__ __launch_bounds__(512, 1) void gemm2f(
    const float* __restrict__ x, const float* __restrict__ v4,
    unsigned short* __restrict__ Ax, const unsigned short* __restrict__ B1,
    const float* __restrict__ c4, const float* __restrict__ bp,
    const float* __restrict__ temp) {
  __shared__ __align__(16) unsigned short as1[2][64 * 32];
  __shared__ __align__(16) unsigned short bs1[2][NB1 * 32];
  __shared__ float ssq_s[2][64];
  __shared__ float xdown_s[64][16];
  __shared__ __align__(16) float dots_s[64][4];
  const int tid = threadIdx.x;
  const int lane = tid & 63, wv = tid >> 6;
  const int wm = wv >> 1, wn = wv & 1;
  const int r0 = blockIdx.x * 64;
  const int ro = lane & 15, ko = (lane >> 4) * 8;
  const int srow = lane >> 2, scol = (lane & 3) * 8;
  const int xr = tid >> 3;
  const int xc = (tid & 7) * 4;
  const float* xgp = &x[(r0 + xr) * DD + xc];
  unsigned short* axp = &Ax[(r0 + xr) * KE + xc];
  f32x4 acc[9] = {};
  float dotp[4] = {};

#define STB1(KT, BUF)                                                         \
  for (int c = wv; c < 18; c += 8)                                            \
    gload16(&B1[(c * 16 + srow) * DD + (KT) * 32 + scol], &bs1[BUF][c * 512]);

#define XSTG(KT, BUF) do {                                                    \
    float4 xv = *(const float4*)(xgp + (KT) * 32);                            \
    float4 va = *(const float4*)&v4[(KT) * 32 + xc];                          \
    float4 vb = *(const float4*)&v4[1024 + (KT) * 32 + xc];                   \
    float4 vc = *(const float4*)&v4[2048 + (KT) * 32 + xc];                   \
    float4 vd = *(const float4*)&v4[3072 + (KT) * 32 + xc];                   \
    dotp[0] = __builtin_fmaf(xv.x, va.x, __builtin_fmaf(xv.y, va.y,           \
              __builtin_fmaf(xv.z, va.z, __builtin_fmaf(xv.w, va.w, dotp[0])))); \
    dotp[1] = __builtin_fmaf(xv.x, vb.x, __builtin_fmaf(xv.y, vb.y,           \
              __builtin_fmaf(xv.z, vb.z, __builtin_fmaf(xv.w, vb.w, dotp[1])))); \
    dotp[2] = __builtin_fmaf(xv.x, vc.x, __builtin_fmaf(xv.y, vc.y,           \
              __builtin_fmaf(xv.z, vc.z, __builtin_fmaf(xv.w, vc.w, dotp[2])))); \
    dotp[3] = __builtin_fmaf(xv.x, vd.x, __builtin_fmaf(xv.y, vd.y,           \
              __builtin_fmaf(xv.z, vd.z, __builtin_fmaf(xv.w, vd.w, dotp[3])))); \
    union { unsigned short s[4]; uint2 q; } pk;                               \
    pk.s[0] = f2bf(xv.x); pk.s[1] = f2bf(xv.y);                               \
    pk.s[2] = f2bf(xv.z); pk.s[3] = f2bf(xv.w);                               \
    *reinterpret_cast<uint2*>(axp + (KT) * 32) = pk.q;                        \
    *reinterpret_cast<uint2*>(&as1[BUF][xr * 32 + xc]) = pk.q;                \
  } while (0)

  XSTG(0, 0);
  STB1(0, 0)
  __syncthreads();
  int cur = 0;
  for (int kt = 0; kt < 32; ++kt) {
    if (kt < 31) {
      XSTG(kt + 1, cur ^ 1);
      STB1(kt + 1, cur ^ 1)
    }
    const unsigned short* ap = &as1[cur][0];
    const unsigned short* bpp = &bs1[cur][0];
    short8 af = *reinterpret_cast<const short8*>(ap + (wm * 16 + ro) * 32 + ko);
#pragma unroll
    for (int n = 0; n < 9; ++n) {
      short8 bf = *reinterpret_cast<const short8*>(bpp + (wn * 144 + n * 16 + ro) * 32 + ko);
      acc[n] = __builtin_amdgcn_mfma_f32_16x16x32_bf16(af, bf, acc[n], 0, 0, 0);
    }
    if (kt < 31) {
      __syncthreads();
      cur ^= 1;
    }
  }

#pragma unroll
  for (int off = 1; off < 8; off <<= 1) {
#pragma unroll
    for (int e = 0; e < 4; ++e) dotp[e] += __shfl_xor(dotp[e], off, 64);
  }
  if ((lane & 7) == 0) {
    dots_s[xr][0] = dotp[0]; dots_s[xr][1] = dotp[1];
    dots_s[xr][2] = dotp[2]; dots_s[xr][3] = dotp[3];
  }

  float ssqp[4] = {};
#pragma unroll
  for (int n = 0; n < 9; ++n) {
    int col = wn * 144 + n * 16 + ro;
    if (col < 256) {
      float b = bp[col];
#pragma unroll
      for (int r = 0; r < 4; ++r) {
        float a = acc[n][r] + b;
        ssqp[r] = __builtin_fmaf(a, a, ssqp[r]);
      }
    }
  }
#pragma unroll
  for (int off = 1; off < 16; off <<= 1) {
#pragma unroll
    for (int r = 0; r < 4; ++r) ssqp[r] += __shfl_xor(ssqp[r], off, 64);
  }
  if (ro == 0) {
#pragma unroll
    for (int r = 0; r < 4; ++r)
      ssq_s[wn][wm * 16 + (lane >> 4) * 4 + r] = ssqp[r];
  }
  if (wn == 1 && ro < 15) {
#pragma unroll
    for (int r = 0; r < 4; ++r)
      xdown_s[wm * 16 + (lane >> 4) * 4 + r][ro] = acc[7][r];
  }
  __syncthreads();

  if (tid < 64) {
    const int row = tid, t = r0 + row;
    float ssqT = ssq_s[0][row] + ssq_s[1][row];
    float4 cc = *reinterpret_cast<const float4*>(c4);
    float scale = expf(fminf(temp[0], CLAMPV));
    float inv = scale / fmaxf(sqrtf(ssqT), 1e-12f);
    float l[4];
    l[0] = (dots_s[row][0] + cc.x) * inv; l[1] = (dots_s[row][1] + cc.y) * inv;
    l[2] = (dots_s[row][2] + cc.z) * inv; l[3] = (dots_s[row][3] + cc.w) * inv;
    int be = 0; float m = l[0];
    if (l[1] > m) { m = l[1]; be = 1; }
    if (l[2] > m) { m = l[2]; be = 2; }
    if (l[3] > m) { m = l[3]; be = 3; }
    float den = expf(l[0] - m) + expf(l[1] - m) + expf(l[2] - m) + expf(l[3] - m);
    float g = 1.0f / den;
    int off = (1 << be) - 1;   // {0,1,3,7}
    int rr = 1 << be;          // {1,2,4,8}
    union { unsigned short s[16]; uint4 v[2]; } o;
#pragma unroll
    for (int j = 0; j < 16; ++j) {
      float dv = xdown_s[row][j & 15];
      float v = (j >= off && j < off + rr) ? g * dv : 0.f;
      o.s[j] = f2bf(v);
    }
    uint4* dst = reinterpret_cast<uint4*>(&Ax[t * KE + 1024]);
    dst[0] = o.v[0];
    dst[1] = o.v[1];
  }
}

// ---------------- kernel 2: main_gemm8 — 256x256 8-phase bf16 MFMA GEMM ----------------
// C[16384,1024] = A[16384,1152] @ B[1024,1152]^T. 512 thr (8 waves 2Mx4N), BK=64,
// 128KB LDS double-buffer, XOR-swizzle (row&7)<<4 both-sides, counted vmcnt(4),
// setprio around MFMA clusters, XCD-chunked block swizzle.
__global__ __launch_bounds__(512, 2) void main_gemm8(
    const unsigned short* __restrict__ A, const unsigned short* __restrict__ Bm,
    float* __restrict__ C) {
  __shared__ __align__(16) unsigned short lbuf[2][32768];  // [buf][A:0..16383 | B:16384..32767]
  const int tid = threadIdx.x;
  const int lane = tid & 63, wv = tid >> 6;
  const int wm = wv >> 2, wn = wv & 3;
  const int dd = blockIdx.x;
  const int tt = (dd & 7) * 32 + (dd >> 3);   // XCD-chunked (256 % 8 == 0, bijective)
  const int bx = tt & 3, by = tt >> 2;
  const int r0 = by * 256, c0 = bx * 256;
  const int ro = lane & 15, ko = (lane >> 4) * 8;
  // frag-read addressing (byte offsets within a 128-row half; swizzled)
  const int rowb = ro * 128;
  const int swz = (ro & 7) << 4;
  const int lk0 = (ko * 2) ^ swz;
  const int lk1 = (64 + ko * 2) ^ swz;
  // stage-side inverse-swizzled source position
  const int ll = (lane * 16) ^ ((lane >> 3) << 4);
  const int sro = ll >> 7;           // 0..7 row-within-8-chunk
  const int sk = (ll & 127) >> 1;    // 0..63 k element
  f32x4 acc[8][4] = {};
  short8 Af[4][2], B0[2][2], B1r[2][2];

  // stage half-tile h of K-tile U2 into lbuf[BUF]: 2 gloads/thread (wave-uniform dest)
#define STG(MTX, GRB, HBU, BUF, U2)                                           \
  do {                                                                        \
    gload16(&MTX[((GRB) + (0 * 8 + wv) * 8 + sro) * KE + (U2) * 64 + sk],     \
            &lbuf[BUF][(HBU) + (0 * 8 + wv) * 512]);                          \
    gload16(&MTX[((GRB) + (1 * 8 + wv) * 8 + sro) * KE + (U2) * 64 + sk],     \
            &lbuf[BUF][(HBU) + (1 * 8 + wv) * 512]);                          \
  } while (0)

#define LDA(FI, QM, LK) (*reinterpret_cast<const short8*>(                    \
    (const char*)Ab + wm * 16384 + (QM) * 8192 + (FI) * 2048 + rowb + (LK)))
#define LDB(FN, QN, LK) (*reinterpret_cast<const short8*>(                    \
    (const char*)Bb + wn * 8192 + (QN) * 4096 + (FN) * 2048 + rowb + (LK)))

#define MMQ(QM, QN, BF)                                                       \
  do {                                                                        \
    _Pragma("unroll")                                                         \
    for (int fi = 0; fi < 4; ++fi) {                                          \
      _Pragma("unroll")                                                       \
      for (int fn = 0; fn < 2; ++fn) {                                        \
        acc[(QM)*4+fi][(QN)*2+fn] = __builtin_amdgcn_mfma_f32_16x16x32_bf16(  \
            Af[fi][0], BF[fn][0], acc[(QM)*4+fi][(QN)*2+fn], 0, 0, 0);        \
        acc[(QM)*4+fi][(QN)*2+fn] = __builtin_amdgcn_mfma_f32_16x16x32_bf16(  \
            Af[fi][1], BF[fn][1], acc[(QM)*4+fi][(QN)*2+fn], 0, 0, 0);        \
      }                                                                       \
    }                                                                         \
  } while (0)

  // ---- prologue: tile0 all 4 halves + tile1 {B-lo, A-lo}; wait for tile0 ----
  STG(Bm, c0,       16384, 0, 0);   // B-lo(0)
  STG(A,  r0,       0,     0, 0);   // A-lo(0)
  STG(Bm, c0 + 128, 24576, 0, 0);   // B-hi(0)
  STG(A,  r0 + 128, 8192,  0, 0);   // A-hi(0)
  STG(Bm, c0,       16384, 1, 1);   // B-lo(1)
  STG(A,  r0,       0,     1, 1);   // A-lo(1)
  asm volatile("s_waitcnt vmcnt(4)" ::: "memory");
  __builtin_amdgcn_s_barrier();

  for (int u = 0; u < NT; ++u) {
    const int db = u & 1;
    const unsigned short* Ab = &lbuf[db][0];
    const unsigned short* Bb = &lbuf[db][16384];
    // ---- phase 0: read A(qm0)+B(qn0); stage B-hi(u+1); MFMA (0,0) ----
#pragma unroll
    for (int fi = 0; fi < 4; ++fi) { Af[fi][0] = LDA(fi, 0, lk0); Af[fi][1] = LDA(fi, 0, lk1); }
#pragma unroll
    for (int fn = 0; fn < 2; ++fn) { B0[fn][0] = LDB(fn, 0, lk0); B0[fn][1] = LDB(fn, 0, lk1); }
    if (u + 1 < NT) STG(Bm, c0 + 128, 24576, (u + 1) & 1, u + 1);
    __builtin_amdgcn_s_barrier();
    __builtin_amdgcn_s_setprio(1);
    MMQ(0, 0, B0);
    __builtin_amdgcn_s_setprio(0);
    __builtin_amdgcn_s_barrier();
    // ---- phase 1: read B(qn1); stage A-hi(u+1); MFMA (0,1) ----
#pragma unroll
    for (int fn = 0; fn < 2; ++fn) { B1r[fn][0] = LDB(fn, 1, lk0); B1r[fn][1] = LDB(fn, 1, lk1); }
    if (u + 1 < NT) STG(A, r0 + 128, 8192, (u + 1) & 1, u + 1);
    __builtin_amdgcn_s_barrier();
    __builtin_amdgcn_s_setprio(1);
    MMQ(0, 1, B1r);
    __builtin_amdgcn_s_setprio(0);
    __builtin_amdgcn_s_barrier();
    // ---- phase 2: read A(qm1); stage B-lo(u+2) into db; MFMA (1,1) ----
#pragma unroll
    for (int fi = 0; fi < 4; ++fi) { Af[fi][0] = LDA(fi, 1, lk0); Af[fi][1] = LDA(fi, 1, lk1); }
    if (u + 2 < NT) STG(Bm, c0, 16384, db, u + 2);
    __builtin_amdgcn_s_barrier();
    __builtin_amdgcn_s_setprio(1);
    MMQ(1, 1, B1r);
    __builtin_amdgcn_s_setprio(0);
    __builtin_amdgcn_s_barrier();
    // ---- phase 3: stage A-lo(u+2) into db; MFMA (1,0); counted vmcnt; barrier ----
    if (u + 2 < NT) STG(A, r0, 0, db, u + 2);
    __builtin_amdgcn_s_barrier();
    __builtin_amdgcn_s_setprio(1);
    MMQ(1, 0, B0);
    __builtin_amdgcn_s_setprio(0);
    if (u + 2 < NT) {
      asm volatile("s_waitcnt vmcnt(4)" ::: "memory");
    } else if (u == NT - 2) {
      asm volatile("s_waitcnt vmcnt(0)" ::: "memory");
    }
    __builtin_amdgcn_s_barrier();
  }

  // ---- epilogue: C write ----
#pragma unroll
  for (int m = 0; m < 8; ++m) {
    int rr = r0 + wm * 128 + m * 16 + (lane >> 4) * 4;
#pragma unroll
    for (int n = 0; n < 4; ++n) {
      int cc = c0 + wn * 64 + n * 16 + ro;
#pragma unroll
      for (int v = 0; v < 4; ++v)
        C[(rr + v) * OO + cc] = acc[m][n][v];
    }
  }
#undef STG
#undef LDA
#undef LDB
#undef MMQ
}

extern "C" void kernel_launch(void* const* d_in, const int* in_sizes, int n_in,
                              void* d_out, int out_size, void* d_ws, size_t ws_size,
                              hipStream_t stream) {
  const float* x    = (const float*)d_in[0];
  const float* W    = (const float*)d_in[1];
  const float* Wp   = (const float*)d_in[2];
  const float* bp   = (const float*)d_in[3];
  const float* sim  = (const float*)d_in[4];
  const float* temp = (const float*)d_in[5];
  const float* Wd0  = (const float*)d_in[6];
  const float* Wu0  = (const float*)d_in[7];
  const float* Wd1  = (const float*)d_in[8];
  const float* Wu1  = (const float*)d_in[9];
  const float* Wd2  = (const float*)d_in[10];
  const float* Wu2  = (const float*)d_in[11];
  const float* Wd3  = (const float*)d_in[12];
  const float* Wu3  = (const float*)d_in[13];
  float* out = (float*)d_out;
  char* ws = (char*)d_ws;
  // ws layout (total 40,714,304 B; ws_size >= 56 MB per round-1):
  unsigned short* Ax  = (unsigned short*)ws;                 // [16384][1152] bf16 = 37,748,736
  unsigned short* Bx  = (unsigned short*)(ws + 37748736);    // [1024][1152] bf16 =  2,359,296
  unsigned short* B1  = (unsigned short*)(ws + 40108032);    // [288][1024] bf16  =    589,824
  float* v4           = (float*)(ws + 40697856);             // [4][1024] f32     =     16,384
  float* c4           = (float*)(ws + 40714240);             // [4] f32           =         64

  prep3<<<1024, 256, 0, stream>>>(W, Wp, sim, bp, Wd0, Wd1, Wd2, Wd3,
                                  Wu0, Wu1, Wu2, Wu3, Bx, B1, Ax, v4, c4);
  gemm2f<<<256, 512, 0, stream>>>(x, v4, Ax, B1, c4, bp, temp);
  main_gemm8<<<256, 512, 0, stream>>>(Ax, Bx, out);
}

// Round 10
// 106.967 us; speedup vs baseline: 2.2116x; 1.0108x over previous
//
#include <hip/hip_runtime.h>

#define TOK 16384
#define DD 1024
#define OO 1024
#define KE 1088     // 1024 + 16 lora cols + 48 zero pad (17 K-tiles of 64)
#define NT 17       // K-tiles in main GEMM
#define NB1 288     // B1 rows: 256 proj + 15 down + 17 zero pad
#define CLAMPV 4.605170185988091f

typedef __attribute__((ext_vector_type(8))) short short8;
typedef __attribute__((ext_vector_type(4))) float f32x4;

__device__ __forceinline__ unsigned short f2bf(float f) {
  unsigned int u = __float_as_uint(f);
  return (unsigned short)((u + 0x7FFFu + ((u >> 16) & 1u)) >> 16);
}

__device__ __forceinline__ void gload16(const unsigned short* g, unsigned short* l) {
  __builtin_amdgcn_global_load_lds(
      (const __attribute__((address_space(1))) void*)g,
      (__attribute__((address_space(3))) void*)l, 16, 0, 0);
}

__device__ __forceinline__ float down_val(int j, int d,
    const float* __restrict__ Wd0, const float* __restrict__ Wd1,
    const float* __restrict__ Wd2, const float* __restrict__ Wd3) {
  if (j == 0) return Wd0[d];
  if (j < 3) return Wd1[(j - 1) * DD + d];
  if (j < 7) return Wd2[(j - 3) * DD + d];
  if (j < 15) return Wd3[(j - 7) * DD + d];
  return 0.f;
}

// ---------------- kernel 0: prep (Bx bf16, B1 bf16, Ax pad, v4 = simn^T Wp, c4 = simn^T bp) ----------------
__global__ __launch_bounds__(256) void prep3(
    const float* __restrict__ W, const float* __restrict__ Wp,
    const float* __restrict__ sim, const float* __restrict__ bp,
    const float* __restrict__ Wd0, const float* __restrict__ Wd1,
    const float* __restrict__ Wd2, const float* __restrict__ Wd3,
    const float* __restrict__ Wu0, const float* __restrict__ Wu1,
    const float* __restrict__ Wu2, const float* __restrict__ Wu3,
    unsigned short* __restrict__ Bx, unsigned short* __restrict__ B1,
    unsigned short* __restrict__ Ax, float* __restrict__ v4,
    float* __restrict__ c4) {
  __shared__ float simn_l[256][4];
  __shared__ float part[4][4];
  const int tid = threadIdx.x;
  if (blockIdx.x < 4) {
    float4 sv = *(const float4*)&sim[tid * 4];
    float v[4] = {sv.x * sv.x, sv.y * sv.y, sv.z * sv.z, sv.w * sv.w};
#pragma unroll
    for (int off = 1; off < 64; off <<= 1) {
#pragma unroll
      for (int e = 0; e < 4; ++e) v[e] += __shfl_xor(v[e], off, 64);
    }
    int wv = tid >> 6, ln = tid & 63;
    if (ln == 0) { part[wv][0] = v[0]; part[wv][1] = v[1]; part[wv][2] = v[2]; part[wv][3] = v[3]; }
    __syncthreads();
    float n0 = fmaxf(sqrtf(part[0][0] + part[1][0] + part[2][0] + part[3][0]), 1e-12f);
    float n1 = fmaxf(sqrtf(part[0][1] + part[1][1] + part[2][1] + part[3][1]), 1e-12f);
    float n2 = fmaxf(sqrtf(part[0][2] + part[1][2] + part[2][2] + part[3][2]), 1e-12f);
    float n3 = fmaxf(sqrtf(part[0][3] + part[1][3] + part[2][3] + part[3][3]), 1e-12f);
    simn_l[tid][0] = sv.x / n0; simn_l[tid][1] = sv.y / n1;
    simn_l[tid][2] = sv.z / n2; simn_l[tid][3] = sv.w / n3;
    __syncthreads();
    int d = blockIdx.x * 256 + tid;
    float a0 = 0.f, a1 = 0.f, a2 = 0.f, a3 = 0.f;
    for (int j = 0; j < 256; ++j) {
      float w = Wp[j * DD + d];
      a0 = __builtin_fmaf(w, simn_l[j][0], a0);
      a1 = __builtin_fmaf(w, simn_l[j][1], a1);
      a2 = __builtin_fmaf(w, simn_l[j][2], a2);
      a3 = __builtin_fmaf(w, simn_l[j][3], a3);
    }
    v4[d] = a0; v4[1024 + d] = a1; v4[2048 + d] = a2; v4[3072 + d] = a3;
    if (blockIdx.x == 0) {
      float bpv = bp[tid];
      float pc[4] = {simn_l[tid][0] * bpv, simn_l[tid][1] * bpv,
                     simn_l[tid][2] * bpv, simn_l[tid][3] * bpv};
#pragma unroll
      for (int off = 1; off < 64; off <<= 1) {
#pragma unroll
        for (int e = 0; e < 4; ++e) pc[e] += __shfl_xor(pc[e], off, 64);
      }
      __syncthreads();
      if (ln == 0) { part[wv][0] = pc[0]; part[wv][1] = pc[1]; part[wv][2] = pc[2]; part[wv][3] = pc[3]; }
      __syncthreads();
      if (tid == 0) {
#pragma unroll
        for (int e = 0; e < 4; ++e)
          c4[e] = part[0][e] + part[1][e] + part[2][e] + part[3][e];
      }
    }
  }
  const int nB1 = NB1 * DD;         // 294912
  const int nWb = OO * KE;          // 1114112
  const int nXpad = TOK * 48;       // 786432 (cols 1040..1087)
  const int total = nB1 + nWb + nXpad;
  for (int i = blockIdx.x * 256 + tid; i < total; i += gridDim.x * 256) {
    if (i < nB1) {
      int r = i >> 10, c = i & 1023;
      float v = 0.f;
      if (r < 256) v = Wp[r * DD + c];
      else if (r < 271) v = down_val(r - 256, c, Wd0, Wd1, Wd2, Wd3);
      B1[i] = f2bf(v);
    } else if (i < nB1 + nWb) {
      int j = i - nB1;
      int o = j / KE, c = j - o * KE;
      float v = 0.f;
      if (c < 1024) v = W[o * DD + c];
      else if (c == 1024) v = Wu0[o];
      else if (c < 1027) v = Wu1[o * 2 + (c - 1025)];
      else if (c < 1031) v = Wu2[o * 4 + (c - 1027)];
      else if (c < 1039) v = Wu3[o * 8 + (c - 1031)];
      Bx[j] = f2bf(v);
    } else {
      int j = i - nB1 - nWb;
      int row = j / 48, c = j - row * 48;
      Ax[row * KE + 1040 + c] = 0;
    }
  }
}

// ---------------- kernel 1: gemm2f — fused x->bf16 + fp32 gate dots + bf16 MFMA
//                  proj/xdown GEMM + gate finalize. Counted-vmcnt pipeline:
//                  per iter drain only B1 gloads; keep {Ax store, x/v4 prefetch}
//                  in flight across the raw s_barrier. ----------------
__global__ __launch_bounds__(512, 1) void gemm2f(
    const float* __restrict__ x, const float* __restrict__ v4,
    unsigned short* __restrict__ Ax, const unsigned short* __restrict__ B1,
    const float* __restrict__ c4, const float* __restrict__ bp,
    const float* __restrict__ temp) {
  __shared__ __align__(16) unsigned short as1[2][64 * 32];
  __shared__ __align__(16) unsigned short bs1[2][NB1 * 32];
  __shared__ float ssq_s[2][64];
  __shared__ float xdown_s[64][16];
  __shared__ __align__(16) float dots_s[64][4];
  const int tid = threadIdx.x;
  const int lane = tid & 63, wv = tid >> 6;
  const int wm = wv >> 1, wn = wv & 1;
  const int r0 = blockIdx.x * 64;
  const int ro = lane & 15, ko = (lane >> 4) * 8;
  const int srow = lane >> 2, scol = (lane & 3) * 8;
  const int xr = tid >> 3;
  const int xc = (tid & 7) * 4;
  const float* xgp = &x[(r0 + xr) * DD + xc];
  unsigned short* axp = &Ax[(r0 + xr) * KE + xc];
  f32x4 acc[9] = {};
  float dotp[4] = {};
  float4 xv, va, vb, vc, vd;      // tile (u+1) operands, held
  float4 xn, na, nb, nc, nd;      // tile (u+2) prefetch

#define STB1(KT, BUF)                                                         \
  for (int c = wv; c < 18; c += 8)                                            \
    gload16(&B1[(c * 16 + srow) * DD + (KT) * 32 + scol], &bs1[BUF][c * 512]);

#define LOADX(KT, X, VA, VB, VC, VD) do {                                     \
    X  = *(const float4*)(xgp + (KT) * 32);                                   \
    VA = *(const float4*)&v4[(KT) * 32 + xc];                                 \
    VB = *(const float4*)&v4[1024 + (KT) * 32 + xc];                          \
    VC = *(const float4*)&v4[2048 + (KT) * 32 + xc];                          \
    VD = *(const float4*)&v4[3072 + (KT) * 32 + xc];                          \
  } while (0)

#define PROC(KT, BUF) do {                                                    \
    dotp[0] = __builtin_fmaf(xv.x, va.x, __builtin_fmaf(xv.y, va.y,           \
              __builtin_fmaf(xv.z, va.z, __builtin_fmaf(xv.w, va.w, dotp[0])))); \
    dotp[1] = __builtin_fmaf(xv.x, vb.x, __builtin_fmaf(xv.y, vb.y,           \
              __builtin_fmaf(xv.z, vb.z, __builtin_fmaf(xv.w, vb.w, dotp[1])))); \
    dotp[2] = __builtin_fmaf(xv.x, vc.x, __builtin_fmaf(xv.y, vc.y,           \
              __builtin_fmaf(xv.z, vc.z, __builtin_fmaf(xv.w, vc.w, dotp[2])))); \
    dotp[3] = __builtin_fmaf(xv.x, vd.x, __builtin_fmaf(xv.y, vd.y,           \
              __builtin_fmaf(xv.z, vd.z, __builtin_fmaf(xv.w, vd.w, dotp[3])))); \
    union { unsigned short s[4]; uint2 q; } pk;                               \
    pk.s[0] = f2bf(xv.x); pk.s[1] = f2bf(xv.y);                               \
    pk.s[2] = f2bf(xv.z); pk.s[3] = f2bf(xv.w);                               \
    *reinterpret_cast<uint2*>(axp + (KT) * 32) = pk.q;                        \
    *reinterpret_cast<uint2*>(&as1[BUF][xr * 32 + xc]) = pk.q;                \
  } while (0)

#define MM(BUF) do {                                                          \
    const unsigned short* ap = &as1[BUF][0];                                  \
    const unsigned short* bpp = &bs1[BUF][0];                                 \
    short8 af = *reinterpret_cast<const short8*>(ap + (wm * 16 + ro) * 32 + ko); \
    _Pragma("unroll")                                                         \
    for (int n = 0; n < 9; ++n) {                                             \
      short8 bf = *reinterpret_cast<const short8*>(                           \
          bpp + (wn * 144 + n * 16 + ro) * 32 + ko);                          \
      acc[n] = __builtin_amdgcn_mfma_f32_16x16x32_bf16(af, bf, acc[n], 0, 0, 0); \
    }                                                                         \
  } while (0)

  // ---- prologue ----
  LOADX(0, xv, va, vb, vc, vd);
  STB1(0, 0)
  __builtin_amdgcn_sched_barrier(0);
  PROC(0, 0);                         // tile 0 into buf 0 (+dots, +Ax store)
  LOADX(1, xn, na, nb, nc, nd);
  asm volatile("s_waitcnt vmcnt(6) lgkmcnt(0)" ::: "memory");
  __builtin_amdgcn_s_barrier();
  xv = xn; va = na; vb = nb; vc = nc; vd = nd;

  for (int u = 0; u < 32; ++u) {
    const int cb = u & 1;
    if (u < 31) {
      STB1(u + 1, cb ^ 1)
      __builtin_amdgcn_sched_barrier(0);
      PROC(u + 1, cb ^ 1);
      if (u < 30) LOADX(u + 2, xn, na, nb, nc, nd);
    }
    MM(cb);
    if (u < 31) {
      if (u < 30) {
        asm volatile("s_waitcnt vmcnt(6) lgkmcnt(0)" ::: "memory");
      } else {
        asm volatile("s_waitcnt vmcnt(1) lgkmcnt(0)" ::: "memory");
      }
      __builtin_amdgcn_s_barrier();
      xv = xn; va = na; vb = nb; vc = nc; vd = nd;
    }
  }

  // ---- fp32 dots: reduce over the 8 lanes sharing a row (lane bits 0..2) ----
#pragma unroll
  for (int off = 1; off < 8; off <<= 1) {
#pragma unroll
    for (int e = 0; e < 4; ++e) dotp[e] += __shfl_xor(dotp[e], off, 64);
  }
  if ((lane & 7) == 0) {
    dots_s[xr][0] = dotp[0]; dots_s[xr][1] = dotp[1];
    dots_s[xr][2] = dotp[2]; dots_s[xr][3] = dotp[3];
  }

  float ssqp[4] = {};
#pragma unroll
  for (int n = 0; n < 9; ++n) {
    int col = wn * 144 + n * 16 + ro;
    if (col < 256) {
      float b = bp[col];
#pragma unroll
      for (int r = 0; r < 4; ++r) {
        float a = acc[n][r] + b;
        ssqp[r] = __builtin_fmaf(a, a, ssqp[r]);
      }
    }
  }
#pragma unroll
  for (int off = 1; off < 16; off <<= 1) {
#pragma unroll
    for (int r = 0; r < 4; ++r) ssqp[r] += __shfl_xor(ssqp[r], off, 64);
  }
  if (ro == 0) {
#pragma unroll
    for (int r = 0; r < 4; ++r)
      ssq_s[wn][wm * 16 + (lane >> 4) * 4 + r] = ssqp[r];
  }
  if (wn == 1 && ro < 15) {
#pragma unroll
    for (int r = 0; r < 4; ++r)
      xdown_s[wm * 16 + (lane >> 4) * 4 + r][ro] = acc[7][r];
  }
  __syncthreads();

  if (tid < 64) {
    const int row = tid, t = r0 + row;
    float ssqT = ssq_s[0][row] + ssq_s[1][row];
    float4 cc = *reinterpret_cast<const float4*>(c4);
    float scale = expf(fminf(temp[0], CLAMPV));
    float inv = scale / fmaxf(sqrtf(ssqT), 1e-12f);
    float l[4];
    l[0] = (dots_s[row][0] + cc.x) * inv; l[1] = (dots_s[row][1] + cc.y) * inv;
    l[2] = (dots_s[row][2] + cc.z) * inv; l[3] = (dots_s[row][3] + cc.w) * inv;
    int be = 0; float m = l[0];
    if (l[1] > m) { m = l[1]; be = 1; }
    if (l[2] > m) { m = l[2]; be = 2; }
    if (l[3] > m) { m = l[3]; be = 3; }
    float den = expf(l[0] - m) + expf(l[1] - m) + expf(l[2] - m) + expf(l[3] - m);
    float g = 1.0f / den;
    int off = (1 << be) - 1;   // {0,1,3,7}
    int rr = 1 << be;          // {1,2,4,8}
    union { unsigned short s[16]; uint4 v[2]; } o;
#pragma unroll
    for (int j = 0; j < 16; ++j) {
      float dv = xdown_s[row][j & 15];
      float v = (j >= off && j < off + rr) ? g * dv : 0.f;
      o.s[j] = f2bf(v);
    }
    uint4* dst = reinterpret_cast<uint4*>(&Ax[t * KE + 1024]);
    dst[0] = o.v[0];
    dst[1] = o.v[1];
  }
#undef STB1
#undef LOADX
#undef PROC
#undef MM
}

// ---------------- kernel 2: main_gemm8 — 256x256 8-phase bf16 MFMA GEMM ----------------
// C[16384,1024] = A[16384,1088] @ B[1024,1088]^T. 512 thr (8 waves 2Mx4N), BK=64,
// 128KB LDS double-buffer, XOR-swizzle (row&7)<<4 both-sides, counted vmcnt(4),
// setprio around MFMA clusters, XCD-chunked block swizzle.
__global__ __launch_bounds__(512, 2) void main_gemm8(
    const unsigned short* __restrict__ A, const unsigned short* __restrict__ Bm,
    float* __restrict__ C) {
  __shared__ __align__(16) unsigned short lbuf[2][32768];  // [buf][A:0..16383 | B:16384..32767]
  const int tid = threadIdx.x;
  const int lane = tid & 63, wv = tid >> 6;
  const int wm = wv >> 2, wn = wv & 3;
  const int dd = blockIdx.x;
  const int tt = (dd & 7) * 32 + (dd >> 3);   // XCD-chunked (256 % 8 == 0, bijective)
  const int bx = tt & 3, by = tt >> 2;
  const int r0 = by * 256, c0 = bx * 256;
  const int ro = lane & 15, ko = (lane >> 4) * 8;
  const int rowb = ro * 128;
  const int swz = (ro & 7) << 4;
  const int lk0 = (ko * 2) ^ swz;
  const int lk1 = (64 + ko * 2) ^ swz;
  const int ll = (lane * 16) ^ ((lane >> 3) << 4);
  const int sro = ll >> 7;
  const int sk = (ll & 127) >> 1;
  f32x4 acc[8][4] = {};
  short8 Af[4][2], B0[2][2], B1r[2][2];

#define STG(MTX, GRB, HBU, BUF, U2)                                           \
  do {                                                                        \
    gload16(&MTX[((GRB) + (0 * 8 + wv) * 8 + sro) * KE + (U2) * 64 + sk],     \
            &lbuf[BUF][(HBU) + (0 * 8 + wv) * 512]);                          \
    gload16(&MTX[((GRB) + (1 * 8 + wv) * 8 + sro) * KE + (U2) * 64 + sk],     \
            &lbuf[BUF][(HBU) + (1 * 8 + wv) * 512]);                          \
  } while (0)

#define LDA(FI, QM, LK) (*reinterpret_cast<const short8*>(                    \
    (const char*)Ab + wm * 16384 + (QM) * 8192 + (FI) * 2048 + rowb + (LK)))
#define LDB(FN, QN, LK) (*reinterpret_cast<const short8*>(                    \
    (const char*)Bb + wn * 8192 + (QN) * 4096 + (FN) * 2048 + rowb + (LK)))

#define MMQ(QM, QN, BF)                                                       \
  do {                                                                        \
    _Pragma("unroll")                                                         \
    for (int fi = 0; fi < 4; ++fi) {                                          \
      _Pragma("unroll")                                                       \
      for (int fn = 0; fn < 2; ++fn) {                                        \
        acc[(QM)*4+fi][(QN)*2+fn] = __builtin_amdgcn_mfma_f32_16x16x32_bf16(  \
            Af[fi][0], BF[fn][0], acc[(QM)*4+fi][(QN)*2+fn], 0, 0, 0);        \
        acc[(QM)*4+fi][(QN)*2+fn] = __builtin_amdgcn_mfma_f32_16x16x32_bf16(  \
            Af[fi][1], BF[fn][1], acc[(QM)*4+fi][(QN)*2+fn], 0, 0, 0);        \
      }                                                                       \
    }                                                                         \
  } while (0)

  STG(Bm, c0,       16384, 0, 0);   // B-lo(0)
  STG(A,  r0,       0,     0, 0);   // A-lo(0)
  STG(Bm, c0 + 128, 24576, 0, 0);   // B-hi(0)
  STG(A,  r0 + 128, 8192,  0, 0);   // A-hi(0)
  STG(Bm, c0,       16384, 1, 1);   // B-lo(1)
  STG(A,  r0,       0,     1, 1);   // A-lo(1)
  asm volatile("s_waitcnt vmcnt(4)" ::: "memory");
  __builtin_amdgcn_s_barrier();

  for (int u = 0; u < NT; ++u) {
    const int db = u & 1;
    const unsigned short* Ab = &lbuf[db][0];
    const unsigned short* Bb = &lbuf[db][16384];
    // phase 0
#pragma unroll
    for (int fi = 0; fi < 4; ++fi) { Af[fi][0] = LDA(fi, 0, lk0); Af[fi][1] = LDA(fi, 0, lk1); }
#pragma unroll
    for (int fn = 0; fn < 2; ++fn) { B0[fn][0] = LDB(fn, 0, lk0); B0[fn][1] = LDB(fn, 0, lk1); }
    if (u + 1 < NT) STG(Bm, c0 + 128, 24576, (u + 1) & 1, u + 1);
    __builtin_amdgcn_s_barrier();
    __builtin_amdgcn_s_setprio(1);
    MMQ(0, 0, B0);
    __builtin_amdgcn_s_setprio(0);
    __builtin_amdgcn_s_barrier();
    // phase 1
#pragma unroll
    for (int fn = 0; fn < 2; ++fn) { B1r[fn][0] = LDB(fn, 1, lk0); B1r[fn][1] = LDB(fn, 1, lk1); }
    if (u + 1 < NT) STG(A, r0 + 128, 8192, (u + 1) & 1, u + 1);
    __builtin_amdgcn_s_barrier();
    __builtin_amdgcn_s_setprio(1);
    MMQ(0, 1, B1r);
    __builtin_amdgcn_s_setprio(0);
    __builtin_amdgcn_s_barrier();
    // phase 2
#pragma unroll
    for (int fi = 0; fi < 4; ++fi) { Af[fi][0] = LDA(fi, 1, lk0); Af[fi][1] = LDA(fi, 1, lk1); }
    if (u + 2 < NT) STG(Bm, c0, 16384, db, u + 2);
    __builtin_amdgcn_s_barrier();
    __builtin_amdgcn_s_setprio(1);
    MMQ(1, 1, B1r);
    __builtin_amdgcn_s_setprio(0);
    __builtin_amdgcn_s_barrier();
    // phase 3
    if (u + 2 < NT) STG(A, r0, 0, db, u + 2);
    __builtin_amdgcn_s_barrier();
    __builtin_amdgcn_s_setprio(1);
    MMQ(1, 0, B0);
    __builtin_amdgcn_s_setprio(0);
    if (u + 2 < NT) {
      asm volatile("s_waitcnt vmcnt(4)" ::: "memory");
    } else if (u == NT - 2) {
      asm volatile("s_waitcnt vmcnt(0)" ::: "memory");
    }
    __builtin_amdgcn_s_barrier();
  }

#pragma unroll
  for (int m = 0; m < 8; ++m) {
    int rr = r0 + wm * 128 + m * 16 + (lane >> 4) * 4;
#pragma unroll
    for (int n = 0; n < 4; ++n) {
      int cc = c0 + wn * 64 + n * 16 + ro;
#pragma unroll
      for (int v = 0; v < 4; ++v)
        C[(rr + v) * OO + cc] = acc[m][n][v];
    }
  }
#undef STG
#undef LDA
#undef LDB
#undef MMQ
}

extern "C" void kernel_launch(void* const* d_in, const int* in_sizes, int n_in,
                              void* d_out, int out_size, void* d_ws, size_t ws_size,
                              hipStream_t stream) {
  const float* x    = (const float*)d_in[0];
  const float* W    = (const float*)d_in[1];
  const float* Wp   = (const float*)d_in[2];
  const float* bp   = (const float*)d_in[3];
  const float* sim  = (const float*)d_in[4];
  const float* temp = (const float*)d_in[5];
  const float* Wd0  = (const float*)d_in[6];
  const float* Wu0  = (const float*)d_in[7];
  const float* Wd1  = (const float*)d_in[8];
  const float* Wu1  = (const float*)d_in[9];
  const float* Wd2  = (const float*)d_in[10];
  const float* Wu2  = (const float*)d_in[11];
  const float* Wd3  = (const float*)d_in[12];
  const float* Wu3  = (const float*)d_in[13];
  float* out = (float*)d_out;
  char* ws = (char*)d_ws;
  // ws layout (total 38,486,080 B):
  unsigned short* Ax  = (unsigned short*)ws;                 // [16384][1088] bf16 = 35,651,584
  unsigned short* Bx  = (unsigned short*)(ws + 35651584);    // [1024][1088] bf16 =  2,228,224
  unsigned short* B1  = (unsigned short*)(ws + 37879808);    // [288][1024] bf16  =    589,824
  float* v4           = (float*)(ws + 38469632);             // [4][1024] f32     =     16,384
  float* c4           = (float*)(ws + 38486016);             // [4] f32           =         64

  prep3<<<1024, 256, 0, stream>>>(W, Wp, sim, bp, Wd0, Wd1, Wd2, Wd3,
                                  Wu0, Wu1, Wu2, Wu3, Bx, B1, Ax, v4, c4);
  gemm2f<<<256, 512, 0, stream>>>(x, v4, Ax, B1, c4, bp, temp);
  main_gemm8<<<256, 512, 0, stream>>>(Ax, Bx, out);
}